// Round 19
// baseline (134.505 us; speedup 1.0000x reference)
//
#include <hip/hip_runtime.h>
#include <math.h>

// MSAPairWeightedAveraging — round 17: m-path reverted to round-15 (proven 53µs k1b);
// k4 operand-swapped MFMA -> packed 8B ob stores (bit-identical values);
// k0+k1a+k2a merged into one k_prep dispatch.
// S=256, N=384, C_M=64, C_Z=128, C=32, H=8, H*C=256.
// ws: mterm f32[384] | wbl bf16[8,384,384] | vT bf16[8,8192,384] | g bf16[98304,256]
//     | ob bf16[98304,256] (aliased as mln pre-k4) | BTg bf16[512,64] | w2bf bf16[16,128] | consts f32[32]

#define SS 256
#define NN 384
#define CM 64
#define CZ 128
#define HH 8
#define HC 256
#define NV 25165824   // S*N*HC

typedef __attribute__((ext_vector_type(8))) short short8v;
typedef __attribute__((ext_vector_type(8))) unsigned short ushort8v;
typedef __attribute__((ext_vector_type(4))) unsigned short ushort4v;
typedef __attribute__((ext_vector_type(4))) float f32x4;

static __device__ __forceinline__ float bf2f(unsigned short u) {
    union { unsigned int i; float f; } x; x.i = ((unsigned int)u) << 16; return x.f;
}
static __device__ __forceinline__ unsigned short f2bf(float f) {
    union { float f; unsigned int i; } x; x.f = f;
    unsigned int r = x.i + 0x7FFFu + ((x.i >> 16) & 1u);   // RNE
    return (unsigned short)(r >> 16);
}
static __device__ __forceinline__ void gload_lds16(const void* g, void* l) {
    __builtin_amdgcn_global_load_lds((const __attribute__((address_space(1))) void*)g,
                                     (__attribute__((address_space(3))) void*)l, 16, 0, 0);
}

// ---------------- k_prep: fused {mask decode | LN-fold w_b | transpose w_v/w_g} ----------------
// block 0: mterm[384]; block 1: w2bf+consts; blocks 2..129: BTg (4 cols each).
__global__ __launch_bounds__(256) void k_prep(
    const unsigned int* __restrict__ mu, const float* __restrict__ lnzw,
    const float* __restrict__ lnzb, const float* __restrict__ w_b,
    const float* __restrict__ w_v, const float* __restrict__ w_g,
    float* __restrict__ mterm, unsigned short* __restrict__ w2bf,
    float* __restrict__ consts, unsigned short* __restrict__ BTg)
{
    const int b = blockIdx.x, tid = threadIdx.x;
    if (b == 0) {
        __shared__ int byteLayout;
        if (tid == 0) byteLayout = 0;
        __syncthreads();
        if (tid < 96) {
            unsigned int u = mu[tid];
            if (u != 0u && u != 1u && u != 0x3F800000u) atomicOr(&byteLayout, 1);
        }
        __syncthreads();
        for (int j = tid; j < 384; j += 256) {
            int val;
            if (byteLayout) val = ((const unsigned char*)mu)[j];
            else            val = (mu[j] != 0u);
            mterm[j] = val ? 0.0f : -1e9f;
        }
    } else if (b == 1) {
        __shared__ float pA[128][8], pB[128][8];
        const int c = tid & 127;
        if (tid < 128) {
            float lw = lnzw[c], lb = lnzb[c];
            float4 wb0 = *(const float4*)&w_b[c * 8];
            float4 wb1 = *(const float4*)&w_b[c * 8 + 4];
            float wv[8] = {wb0.x, wb0.y, wb0.z, wb0.w, wb1.x, wb1.y, wb1.z, wb1.w};
            #pragma unroll
            for (int h = 0; h < 8; h++) {
                w2bf[h * CZ + c]       = f2bf(lw * wv[h]);
                w2bf[(8 + h) * CZ + c] = 0;
                pA[c][h] = lw * wv[h];
                pB[c][h] = lb * wv[h];
            }
        }
        __syncthreads();
        if (tid < 8) {
            float A = 0.f, B = 0.f;
            for (int q = 0; q < 128; q++) { A += pA[q][tid]; B += pB[q][tid]; }
            consts[tid] = A; consts[16 + tid] = B;
            consts[8 + tid] = 0.f; consts[24 + tid] = 0.f;
        }
    } else {
        const int col = (b - 2) * 4 + (tid >> 6);
        const int k   = tid & 63;
        float w = (col < 256) ? w_v[k * 256 + col] : w_g[k * 256 + (col - 256)];
        BTg[col * 64 + (k ^ ((col & 7) << 3))] = f2bf(w);
    }
}

// ---------------- k1n: LN(m) -> mln bf16 [98304][64], pre-swizzled within rows ----------------
__global__ __launch_bounds__(256) void k1n_ln(
    const float* __restrict__ m, const float* __restrict__ lnw, const float* __restrict__ lnb,
    unsigned short* __restrict__ mln)
{
    const int tid = threadIdx.x, wid = tid >> 6, lane = tid & 63;
    const int rowBase = blockIdx.x * 64 + wid * 16;
    const float lw = lnw[lane], lb = lnb[lane];
    #pragma unroll 4
    for (int rr = 0; rr < 16; rr++) {
        int row = rowBase + rr;
        float x = m[(size_t)row * CM + lane];
        float s1 = x, s2 = x * x;
        #pragma unroll
        for (int off = 32; off; off >>= 1) {
            s1 += __shfl_xor(s1, off);
            s2 += __shfl_xor(s2, off);
        }
        float mu  = s1 * (1.0f / CM);
        float var = s2 * (1.0f / CM) - mu * mu;
        float y = (x - mu) * rsqrtf(var + 1e-5f) * lw + lb;
        mln[(size_t)row * CM + (lane ^ ((row & 7) << 3))] = f2bf(y);
    }
}

// ---------------- k1b: barrier-free merged GEMM (round-15 exact) ----------------
__global__ __launch_bounds__(256) void k1b_vg(
    const unsigned short* __restrict__ BTg, const unsigned short* __restrict__ mln,
    unsigned short* __restrict__ vT, unsigned short* __restrict__ gout)
{
    __shared__ unsigned short Wl[32768];  // [512 cols][64 k] swizzled; wave-partitioned by col
    __shared__ unsigned short Al[4096];   // [64 rows][64 k] swizzled; redundantly staged
    const int tid = threadIdx.x, wid = tid >> 6, lane = tid & 63;
    const int rl = lane & 15, kc = lane >> 4;
    const int rowBase = blockIdx.x * 64;       // 64 | 384 -> never straddles s
    const int s = rowBase / NN, j0 = rowBase - s * NN;

    #pragma unroll
    for (int it = 0; it < 8; it++) {
        int eoff = wid * 4096 + it * 512;
        gload_lds16(BTg + eoff + lane * 8, (void*)((char*)Wl + eoff * 2));
    }
    #pragma unroll
    for (int it = 0; it < 8; it++) {
        int eoff = 16384 + wid * 4096 + it * 512;
        gload_lds16(BTg + eoff + lane * 8, (void*)((char*)Wl + eoff * 2));
    }
    #pragma unroll
    for (int it = 0; it < 8; it++) {
        int eoff = it * 512;
        gload_lds16(mln + (size_t)rowBase * CM + eoff + lane * 8, (void*)((char*)Al + eoff * 2));
    }
    asm volatile("s_waitcnt vmcnt(0)" ::: "memory");
    __builtin_amdgcn_sched_barrier(0);

    short8v al[2][4];
    #pragma unroll
    for (int ks = 0; ks < 2; ks++)
        #pragma unroll
        for (int q = 0; q < 4; q++) {
            int row = q * 16 + rl;
            al[ks][q] = *(const short8v*)&Al[(row * 64 + ks * 32 + kc * 8) ^ ((row & 7) << 3)];
        }

    unsigned short* VS = Wl + wid * 4096;   // wave-private 8KB scratch

    // v-part
    {
        f32x4 acc[4][4] = {};
        #pragma unroll
        for (int ks = 0; ks < 2; ks++) {
            short8v wf[4];
            #pragma unroll
            for (int q = 0; q < 4; q++) {
                int col = wid * 64 + q * 16 + rl;
                wf[q] = *(const short8v*)&Wl[(col * 64 + ks * 32 + kc * 8) ^ ((col & 7) << 3)];
            }
            #pragma unroll
            for (int mi = 0; mi < 4; mi++)
                #pragma unroll
                for (int nf = 0; nf < 4; nf++)
                    acc[mi][nf] = __builtin_amdgcn_mfma_f32_16x16x32_bf16(al[ks][mi], wf[nf], acc[mi][nf], 0, 0, 0);
        }
        #pragma unroll
        for (int mi = 0; mi < 4; mi++) {
            const int jb = mi * 16 + kc * 4;
            #pragma unroll
            for (int nf = 0; nf < 4; nf++) {
                int hcl = nf * 16 + rl;
                ushort4v o4;
                #pragma unroll
                for (int r = 0; r < 4; r++) o4[r] = f2bf(acc[mi][nf][r]);
                *(ushort4v*)&VS[(hcl * 64 + jb) ^ ((hcl & 7) << 3)] = o4;
            }
        }
        #pragma unroll
        for (int p = 0; p < 8; p++) {
            int hcl = p * 8 + (lane >> 3);
            int j8  = (lane & 7) * 8;
            ushort8v val = *(const ushort8v*)&VS[(hcl * 64 + j8) ^ ((hcl & 7) << 3)];
            int hc = wid * 64 + hcl;
            size_t vrow = (size_t)((hc >> 5) * 8192 + s * 32 + (hc & 31));
            *(ushort8v*)&vT[vrow * NN + j0 + j8] = val;
        }
    }

    // g-part
    {
        f32x4 acc[4][4] = {};
        #pragma unroll
        for (int ks = 0; ks < 2; ks++) {
            short8v wf[4];
            #pragma unroll
            for (int q = 0; q < 4; q++) {
                int col = 256 + wid * 64 + q * 16 + rl;
                wf[q] = *(const short8v*)&Wl[(col * 64 + ks * 32 + kc * 8) ^ ((col & 7) << 3)];
            }
            #pragma unroll
            for (int mi = 0; mi < 4; mi++)
                #pragma unroll
                for (int nf = 0; nf < 4; nf++)
                    acc[mi][nf] = __builtin_amdgcn_mfma_f32_16x16x32_bf16(wf[mi], al[ks][nf], acc[mi][nf], 0, 0, 0);
        }
        #pragma unroll
        for (int mi = 0; mi < 4; mi++) {
            const int hcb = mi * 16 + kc * 4;
            #pragma unroll
            for (int nf = 0; nf < 4; nf++) {
                int rowl = nf * 16 + rl;
                ushort4v o4;
                #pragma unroll
                for (int r = 0; r < 4; r++)
                    o4[r] = f2bf(1.0f / (1.0f + __expf(-acc[mi][nf][r])));
                *(ushort4v*)&VS[(rowl * 64 + hcb) ^ ((rowl & 7) << 3)] = o4;
            }
        }
        #pragma unroll
        for (int p = 0; p < 8; p++) {
            int rowl = p * 8 + (lane >> 3);
            int hc8  = (lane & 7) * 8;
            ushort8v val = *(const ushort8v*)&VS[(rowl * 64 + hc8) ^ ((rowl & 7) << 3)];
            *(ushort8v*)&gout[(size_t)(rowBase + rowl) * HC + wid * 64 + hc8] = val;
        }
    }
}

// ---------------- k2: MFMA projection: b = rstd*(z@W2) - rstd*mu*A + B + mask ----------------
__global__ __launch_bounds__(256) void k2_mfma(
    const float* __restrict__ z, const unsigned short* __restrict__ w2bf,
    const float* __restrict__ consts, const float* __restrict__ mterm,
    unsigned short* __restrict__ wbl)
{
    __shared__ float st[4][16][2];
    const int tid = threadIdx.x, wid = tid >> 6, lane = tid & 63;
    const int rl = lane & 15, kc = lane >> 4;
    const int rowBase = blockIdx.x * 64 + wid * 16;
    const int i = rowBase / NN, j0 = rowBase - i * NN;
    const float* zr = z + (size_t)(rowBase + rl) * CZ + kc * 8;

    float s1 = 0.f, s2 = 0.f;
    short8v af[4];
    #pragma unroll
    for (int ks = 0; ks < 4; ks++) {
        float4 z0 = *(const float4*)(zr + ks * 32);
        float4 z1 = *(const float4*)(zr + ks * 32 + 4);
        float zz[8] = {z0.x, z0.y, z0.z, z0.w, z1.x, z1.y, z1.z, z1.w};
        short8v a;
        #pragma unroll
        for (int q = 0; q < 8; q++) {
            s1 += zz[q];
            s2 += zz[q] * zz[q];
            a[q] = (short)f2bf(zz[q]);
        }
        af[ks] = a;
    }
    s1 += __shfl_xor(s1, 16); s2 += __shfl_xor(s2, 16);
    s1 += __shfl_xor(s1, 32); s2 += __shfl_xor(s2, 32);
    if (kc == 0) { st[wid][rl][0] = s1; st[wid][rl][1] = s2; }

    f32x4 acc = {};
    #pragma unroll
    for (int ks = 0; ks < 4; ks++) {
        short8v b = *(const short8v*)&w2bf[rl * CZ + ks * 32 + kc * 8];
        acc = __builtin_amdgcn_mfma_f32_16x16x32_bf16(af[ks], b, acc, 0, 0, 0);
    }
    __syncthreads();

    const float Ah = consts[rl], Bh = consts[16 + rl];
    unsigned short pv[4];
    #pragma unroll
    for (int reg = 0; reg < 4; reg++) {
        int r = 4 * kc + reg;
        float S1 = st[wid][r][0], S2 = st[wid][r][1];
        float mu   = S1 * (1.0f / CZ);
        float var  = S2 * (1.0f / CZ) - mu * mu;
        float rstd = rsqrtf(var + 1e-5f);
        float b = rstd * acc[reg] - rstd * mu * Ah + Bh + mterm[j0 + r];
        pv[reg] = f2bf(b);
    }
    if (rl < 8) {
        ushort4v o4 = {pv[0], pv[1], pv[2], pv[3]};
        *(ushort4v*)&wbl[((size_t)rl * NN + i) * NN + j0 + 4 * kc] = o4;
    }
}

// ---------------- k3: softmax over j, bf16 in place on wbl[h][i][:] ----------------
__global__ __launch_bounds__(256) void k3_softmax(unsigned short* __restrict__ wbl)
{
    const int tid = threadIdx.x, wave = tid >> 6, lane = tid & 63;
    const int row = blockIdx.x * 4 + wave;   // = h*384 + i
    unsigned short* p = wbl + (size_t)row * NN;
    float x[6];
    float mx = -1e30f;
    #pragma unroll
    for (int e = 0; e < 6; e++) { x[e] = bf2f(p[lane + e * 64]); mx = fmaxf(mx, x[e]); }
    #pragma unroll
    for (int off = 32; off; off >>= 1) mx = fmaxf(mx, __shfl_xor(mx, off));
    float sum = 0.f;
    #pragma unroll
    for (int e = 0; e < 6; e++) { x[e] = expf(x[e] - mx); sum += x[e]; }
    #pragma unroll
    for (int off = 32; off; off >>= 1) sum += __shfl_xor(sum, off);
    float inv = 1.0f / sum;
    #pragma unroll
    for (int e = 0; e < 6; e++) p[lane + e * 64] = f2bf(x[e] * inv);
}

// ---------------- k4: per-h MFMA GEMM; operand-swapped -> packed 8B ob stores ----------------
__global__ __launch_bounds__(256) void k4_mfma(
    const unsigned short* __restrict__ wbf, const unsigned short* __restrict__ vT,
    unsigned short* __restrict__ ob)
{
    __shared__ unsigned short Al[128 * 32];
    __shared__ unsigned short Bl[128 * 32];
    const int tid  = threadIdx.x;
    const int wid  = tid >> 6, lane = tid & 63;
    const int wm   = wid >> 1, wn = wid & 1;
    const int h    = blockIdx.z;
    const int i0   = blockIdx.y * 128;
    const int n0   = blockIdx.x * 128;
    const unsigned short* Ag = wbf + (size_t)h * NN * NN;
    const unsigned short* Bg = vT  + (size_t)h * 8192 * NN;

    f32x4 acc[4][4] = {};

    const int lrow = lane >> 2, lchunk = lane & 3;
    for (int k0 = 0; k0 < NN; k0 += 32) {
        #pragma unroll
        for (int q = 0; q < 2; q++) {
            int issue = wid * 2 + q;
            int r = issue * 16 + lrow;
            gload_lds16(Ag + (size_t)(i0 + r) * NN + k0 + lchunk * 8,
                        (void*)((char*)Al + issue * 1024));
            gload_lds16(Bg + (size_t)(n0 + r) * NN + k0 + lchunk * 8,
                        (void*)((char*)Bl + issue * 1024));
        }
        __syncthreads();

        short8v a[4], b[4];
        #pragma unroll
        for (int mi = 0; mi < 4; mi++)
            a[mi] = *(const short8v*)&Al[(wm * 64 + mi * 16 + (lane & 15)) * 32 + (lane >> 4) * 8];
        #pragma unroll
        for (int ni = 0; ni < 4; ni++)
            b[ni] = *(const short8v*)&Bl[(wn * 64 + ni * 16 + (lane & 15)) * 32 + (lane >> 4) * 8];
        // swapped operands: reg-dim = sc (Bl rows), lane-dim = i (Al rows); same products/order
        #pragma unroll
        for (int mi = 0; mi < 4; mi++)
            #pragma unroll
            for (int ni = 0; ni < 4; ni++)
                acc[mi][ni] = __builtin_amdgcn_mfma_f32_16x16x32_bf16(b[ni], a[mi], acc[mi][ni], 0, 0, 0);
        __syncthreads();
    }

    // D: lane = i (col dim), reg = sc (row dim). 4 consecutive sc stay within one s-block.
    #pragma unroll
    for (int mi = 0; mi < 4; mi++) {
        const int i = i0 + wm * 64 + mi * 16 + (lane & 15);
        #pragma unroll
        for (int ni = 0; ni < 4; ni++) {
            const int sc0 = n0 + wn * 64 + ni * 16 + ((lane >> 4) << 2);
            const int s = sc0 >> 5, c0 = sc0 & 31;
            ushort4v o4;
            #pragma unroll
            for (int r = 0; r < 4; r++) o4[r] = f2bf(acc[mi][ni][r]);
            *(ushort4v*)&ob[((size_t)s * NN + i) * HC + (h << 5) + c0] = o4;
        }
    }
}

// ---------------- k5: out[98304,64] = (o .* g)[98304,256] @ w_out[256,64]  via MFMA ----------------
__global__ __launch_bounds__(256) void k5_mfma(
    const unsigned short* __restrict__ ob, const unsigned short* __restrict__ g,
    const float* __restrict__ w_out, float* __restrict__ out)
{
    __shared__ unsigned short WT[64 * 256];   // w_out^T bf16, swizzled: idx ^ ((c&7)<<3)
    const int tid = threadIdx.x, wid = tid >> 6, lane = tid & 63;
    #pragma unroll
    for (int e = 0; e < 16; e++) {
        int fidx = (tid + e * 256) * 4;
        float4 w4 = *(const float4*)&w_out[fidx];
        int k = fidx >> 6, c0 = fidx & 63;
        float wv[4] = {w4.x, w4.y, w4.z, w4.w};
        #pragma unroll
        for (int q = 0; q < 4; q++) {
            int c = c0 + q;
            WT[(((c << 8) + k)) ^ ((c & 7) << 3)] = f2bf(wv[q]);
        }
    }
    __syncthreads();

    const size_t rowbase = (size_t)blockIdx.x * 64 + wid * 16;
    const int arow = lane & 15, achunk = lane >> 4;
    const unsigned short* op = ob + (rowbase + arow) * HC + achunk * 8;
    const unsigned short* gp = g  + (rowbase + arow) * HC + achunk * 8;

    f32x4 acc[4] = {};
    #pragma unroll
    for (int ks = 0; ks < 8; ks++) {
        ushort8v o8 = *(const ushort8v*)(op + ks * 32);
        ushort8v g8 = *(const ushort8v*)(gp + ks * 32);
        short8v a;
        #pragma unroll
        for (int q = 0; q < 8; q++)
            a[q] = (short)f2bf(bf2f(o8[q]) * bf2f(g8[q]));
        #pragma unroll
        for (int nf = 0; nf < 4; nf++) {
            const int c = nf * 16 + arow;
            short8v b = *(const short8v*)&WT[(((c << 8) + ks * 32 + achunk * 8)) ^ ((c & 7) << 3)];
            acc[nf] = __builtin_amdgcn_mfma_f32_16x16x32_bf16(a, b, acc[nf], 0, 0, 0);
        }
    }
    #pragma unroll
    for (int nf = 0; nf < 4; nf++)
        #pragma unroll
        for (int r = 0; r < 4; r++)
            out[(rowbase + achunk * 4 + r) * CM + nf * 16 + arow] = acc[nf][r];
}

extern "C" void kernel_launch(void* const* d_in, const int* in_sizes, int n_in,
                              void* d_out, int out_size, void* d_ws, size_t ws_size,
                              hipStream_t stream)
{
    const float* m      = (const float*)d_in[0];
    const float* z      = (const float*)d_in[1];
    const unsigned int* mask_raw = (const unsigned int*)d_in[2];
    const float* ln_m_w = (const float*)d_in[3];
    const float* ln_m_b = (const float*)d_in[4];
    const float* ln_z_w = (const float*)d_in[5];
    const float* ln_z_b = (const float*)d_in[6];
    const float* w_v    = (const float*)d_in[7];
    const float* w_b    = (const float*)d_in[8];
    const float* w_g    = (const float*)d_in[9];
    const float* w_out  = (const float*)d_in[10];
    float* out = (float*)d_out;

    // ws layout
    float* mterm = (float*)d_ws;
    unsigned short* wbl = (unsigned short*)(mterm + 384);
    unsigned short* vT  = wbl + 1179648;
    unsigned short* g   = vT + NV;
    unsigned short* ob  = g + NV;
    unsigned short* BTg = ob + NV;             // [512][64]
    unsigned short* w2bf = BTg + 32768;        // [16][128]
    float* consts = (float*)(w2bf + 2048);     // [32]
    unsigned short* mln = ob;                  // alias: dead before k4 writes ob

    k_prep<<<130, 256, 0, stream>>>(mask_raw, ln_z_w, ln_z_b, w_b, w_v, w_g,
                                    mterm, w2bf, consts, BTg);
    k1n_ln<<<1536, 256, 0, stream>>>(m, ln_m_w, ln_m_b, mln);
    k1b_vg<<<1536, 256, 0, stream>>>(BTg, mln, vT, g);
    k2_mfma<<<2304, 256, 0, stream>>>(z, w2bf, consts, mterm, wbl);
    k3_softmax<<<768, 256, 0, stream>>>(wbl);
    k4_mfma<<<dim3(64, 3, 8), 256, 0, stream>>>(wbl, vT, ob);
    k5_mfma<<<1536, 256, 0, stream>>>(ob, g, w_out, out);
}

// Round 20
// 131.871 us; speedup vs baseline: 1.0200x; 1.0200x over previous
//
#include <hip/hip_runtime.h>
#include <math.h>

// MSAPairWeightedAveraging — round 19: k1b re-partitioned to 512-thread blocks,
// 8 waves x ONE family each (wave-private W staging, redundant A, zero barriers).
// Same arithmetic as the passing round-17 kernel -> identical absmax.
// S=256, N=384, C_M=64, C_Z=128, C=32, H=8, H*C=256.
// ws: mterm f32[384] | wbl bf16[8,384,384] | vT bf16[8,8192,384] | g bf16[98304,256]
//     | ob bf16[98304,256] (aliased as mln pre-k4) | BTg bf16[512,64] | w2bf bf16[16,128] | consts f32[32]

#define SS 256
#define NN 384
#define CM 64
#define CZ 128
#define HH 8
#define HC 256
#define NV 25165824   // S*N*HC

typedef __attribute__((ext_vector_type(8))) short short8v;
typedef __attribute__((ext_vector_type(8))) unsigned short ushort8v;
typedef __attribute__((ext_vector_type(4))) unsigned short ushort4v;
typedef __attribute__((ext_vector_type(4))) float f32x4;

static __device__ __forceinline__ float bf2f(unsigned short u) {
    union { unsigned int i; float f; } x; x.i = ((unsigned int)u) << 16; return x.f;
}
static __device__ __forceinline__ unsigned short f2bf(float f) {
    union { float f; unsigned int i; } x; x.f = f;
    unsigned int r = x.i + 0x7FFFu + ((x.i >> 16) & 1u);   // RNE
    return (unsigned short)(r >> 16);
}
static __device__ __forceinline__ void gload_lds16(const void* g, void* l) {
    __builtin_amdgcn_global_load_lds((const __attribute__((address_space(1))) void*)g,
                                     (__attribute__((address_space(3))) void*)l, 16, 0, 0);
}

// ---------------- k_prep: fused {mask decode | LN-fold w_b | transpose w_v/w_g} ----------------
__global__ __launch_bounds__(256) void k_prep(
    const unsigned int* __restrict__ mu, const float* __restrict__ lnzw,
    const float* __restrict__ lnzb, const float* __restrict__ w_b,
    const float* __restrict__ w_v, const float* __restrict__ w_g,
    float* __restrict__ mterm, unsigned short* __restrict__ w2bf,
    float* __restrict__ consts, unsigned short* __restrict__ BTg)
{
    const int b = blockIdx.x, tid = threadIdx.x;
    if (b == 0) {
        __shared__ int byteLayout;
        if (tid == 0) byteLayout = 0;
        __syncthreads();
        if (tid < 96) {
            unsigned int u = mu[tid];
            if (u != 0u && u != 1u && u != 0x3F800000u) atomicOr(&byteLayout, 1);
        }
        __syncthreads();
        for (int j = tid; j < 384; j += 256) {
            int val;
            if (byteLayout) val = ((const unsigned char*)mu)[j];
            else            val = (mu[j] != 0u);
            mterm[j] = val ? 0.0f : -1e9f;
        }
    } else if (b == 1) {
        __shared__ float pA[128][8], pB[128][8];
        const int c = tid & 127;
        if (tid < 128) {
            float lw = lnzw[c], lb = lnzb[c];
            float4 wb0 = *(const float4*)&w_b[c * 8];
            float4 wb1 = *(const float4*)&w_b[c * 8 + 4];
            float wv[8] = {wb0.x, wb0.y, wb0.z, wb0.w, wb1.x, wb1.y, wb1.z, wb1.w};
            #pragma unroll
            for (int h = 0; h < 8; h++) {
                w2bf[h * CZ + c]       = f2bf(lw * wv[h]);
                w2bf[(8 + h) * CZ + c] = 0;
                pA[c][h] = lw * wv[h];
                pB[c][h] = lb * wv[h];
            }
        }
        __syncthreads();
        if (tid < 8) {
            float A = 0.f, B = 0.f;
            for (int q = 0; q < 128; q++) { A += pA[q][tid]; B += pB[q][tid]; }
            consts[tid] = A; consts[16 + tid] = B;
            consts[8 + tid] = 0.f; consts[24 + tid] = 0.f;
        }
    } else {
        const int col = (b - 2) * 4 + (tid >> 6);
        const int k   = tid & 63;
        float w = (col < 256) ? w_v[k * 256 + col] : w_g[k * 256 + (col - 256)];
        BTg[col * 64 + (k ^ ((col & 7) << 3))] = f2bf(w);
    }
}

// ---------------- k1n: LN(m) -> mln bf16 [98304][64], pre-swizzled within rows ----------------
__global__ __launch_bounds__(256) void k1n_ln(
    const float* __restrict__ m, const float* __restrict__ lnw, const float* __restrict__ lnb,
    unsigned short* __restrict__ mln)
{
    const int tid = threadIdx.x, wid = tid >> 6, lane = tid & 63;
    const int rowBase = blockIdx.x * 64 + wid * 16;
    const float lw = lnw[lane], lb = lnb[lane];
    #pragma unroll 4
    for (int rr = 0; rr < 16; rr++) {
        int row = rowBase + rr;
        float x = m[(size_t)row * CM + lane];
        float s1 = x, s2 = x * x;
        #pragma unroll
        for (int off = 32; off; off >>= 1) {
            s1 += __shfl_xor(s1, off);
            s2 += __shfl_xor(s2, off);
        }
        float mu  = s1 * (1.0f / CM);
        float var = s2 * (1.0f / CM) - mu * mu;
        float y = (x - mu) * rsqrtf(var + 1e-5f) * lw + lb;
        mln[(size_t)row * CM + (lane ^ ((row & 7) << 3))] = f2bf(y);
    }
}

// ---------------- k1b: 8-wave one-family-per-wave barrier-free GEMM ----------------
// grid 1536 x 512 threads. wave wid: fam = wid>>2 (0:v, 1:g), wq = wid&3 (64-col quarter).
// Wave stages its own 64 W cols (8 gload_lds) + redundant A; vmcnt(0); 32 MFMA; one epilogue.
__global__ __launch_bounds__(512) void k1b_vg(
    const unsigned short* __restrict__ BTg, const unsigned short* __restrict__ mln,
    unsigned short* __restrict__ vT, unsigned short* __restrict__ gout)
{
    __shared__ unsigned short Wl[32768];  // [512 cols][64 k] swizzled; wave-partitioned (8KB/wave)
    __shared__ unsigned short Al[4096];   // [64 rows][64 k] swizzled; redundantly staged
    const int tid = threadIdx.x, wid = tid >> 6, lane = tid & 63;
    const int rl = lane & 15, kc = lane >> 4;
    const int fam = wid >> 2, wq = wid & 3;
    const int rowBase = blockIdx.x * 64;       // 64 | 384 -> never straddles s
    const int s = rowBase / NN, j0 = rowBase - s * NN;

    // wave-private W staging: 64 cols starting at fam*256 + wq*64
    #pragma unroll
    for (int it = 0; it < 8; it++) {
        int eoff = wid * 4096 + it * 512;          // == (fam*16384 + wq*4096) + it*512
        gload_lds16(BTg + eoff + lane * 8, (void*)((char*)Wl + eoff * 2));
    }
    // redundant A staging (identical bytes from all 8 waves -> benign race)
    #pragma unroll
    for (int it = 0; it < 8; it++) {
        int eoff = it * 512;
        gload_lds16(mln + (size_t)rowBase * CM + eoff + lane * 8, (void*)((char*)Al + eoff * 2));
    }
    asm volatile("s_waitcnt vmcnt(0)" ::: "memory");
    __builtin_amdgcn_sched_barrier(0);

    // A fragments
    short8v al[2][4];
    #pragma unroll
    for (int ks = 0; ks < 2; ks++)
        #pragma unroll
        for (int q = 0; q < 4; q++) {
            int row = q * 16 + rl;
            al[ks][q] = *(const short8v*)&Al[(row * 64 + ks * 32 + kc * 8) ^ ((row & 7) << 3)];
        }

    unsigned short* WP = Wl + wid * 4096;   // this wave's 8KB W region (cols local 0..63)
    unsigned short* VS = WP;                // reused as wave-private scratch after wf reads

    f32x4 acc[4][4] = {};
    if (fam == 0) {
        // v: A=al so j lands in reg dim
        #pragma unroll
        for (int ks = 0; ks < 2; ks++) {
            short8v wf[4];
            #pragma unroll
            for (int q = 0; q < 4; q++) {
                int cl = q * 16 + rl;   // local col; global col = wq*64+cl, (col&7)==(cl&7)
                wf[q] = *(const short8v*)&WP[(cl * 64 + ks * 32 + kc * 8) ^ ((cl & 7) << 3)];
            }
            #pragma unroll
            for (int mi = 0; mi < 4; mi++)
                #pragma unroll
                for (int nf = 0; nf < 4; nf++)
                    acc[mi][nf] = __builtin_amdgcn_mfma_f32_16x16x32_bf16(al[ks][mi], wf[nf], acc[mi][nf], 0, 0, 0);
        }
        // stage to wave-private LDS: VS[hcl][j], elem ^= (hcl&7)<<3
        #pragma unroll
        for (int mi = 0; mi < 4; mi++) {
            const int jb = mi * 16 + kc * 4;
            #pragma unroll
            for (int nf = 0; nf < 4; nf++) {
                int hcl = nf * 16 + rl;
                ushort4v o4;
                #pragma unroll
                for (int r = 0; r < 4; r++) o4[r] = f2bf(acc[mi][nf][r]);
                *(ushort4v*)&VS[(hcl * 64 + jb) ^ ((hcl & 7) << 3)] = o4;
            }
        }
        #pragma unroll
        for (int p = 0; p < 8; p++) {
            int hcl = p * 8 + (lane >> 3);
            int j8  = (lane & 7) * 8;
            ushort8v val = *(const ushort8v*)&VS[(hcl * 64 + j8) ^ ((hcl & 7) << 3)];
            int hc = wq * 64 + hcl;
            size_t vrow = (size_t)((hc >> 5) * 8192 + s * 32 + (hc & 31));
            *(ushort8v*)&vT[vrow * NN + j0 + j8] = val;
        }
    } else {
        // g: A=wf so hc lands in reg dim
        #pragma unroll
        for (int ks = 0; ks < 2; ks++) {
            short8v wf[4];
            #pragma unroll
            for (int q = 0; q < 4; q++) {
                int cl = q * 16 + rl;
                wf[q] = *(const short8v*)&WP[(cl * 64 + ks * 32 + kc * 8) ^ ((cl & 7) << 3)];
            }
            #pragma unroll
            for (int mi = 0; mi < 4; mi++)
                #pragma unroll
                for (int nf = 0; nf < 4; nf++)
                    acc[mi][nf] = __builtin_amdgcn_mfma_f32_16x16x32_bf16(wf[mi], al[ks][nf], acc[mi][nf], 0, 0, 0);
        }
        // stage to LDS: VS[rowl][hc_local], elem ^= (rowl&7)<<3
        #pragma unroll
        for (int mi = 0; mi < 4; mi++) {
            const int hcb = mi * 16 + kc * 4;   // local hc 0..63
            #pragma unroll
            for (int nf = 0; nf < 4; nf++) {
                int rowl = nf * 16 + rl;
                ushort4v o4;
                #pragma unroll
                for (int r = 0; r < 4; r++)
                    o4[r] = f2bf(1.0f / (1.0f + __expf(-acc[mi][nf][r])));
                *(ushort4v*)&VS[(rowl * 64 + hcb) ^ ((rowl & 7) << 3)] = o4;
            }
        }
        #pragma unroll
        for (int p = 0; p < 8; p++) {
            int rowl = p * 8 + (lane >> 3);
            int hc8  = (lane & 7) * 8;
            ushort8v val = *(const ushort8v*)&VS[(rowl * 64 + hc8) ^ ((rowl & 7) << 3)];
            *(ushort8v*)&gout[(size_t)(rowBase + rowl) * HC + wq * 64 + hc8] = val;
        }
    }
}

// ---------------- k2: MFMA projection: b = rstd*(z@W2) - rstd*mu*A + B + mask ----------------
__global__ __launch_bounds__(256) void k2_mfma(
    const float* __restrict__ z, const unsigned short* __restrict__ w2bf,
    const float* __restrict__ consts, const float* __restrict__ mterm,
    unsigned short* __restrict__ wbl)
{
    __shared__ float st[4][16][2];
    const int tid = threadIdx.x, wid = tid >> 6, lane = tid & 63;
    const int rl = lane & 15, kc = lane >> 4;
    const int rowBase = blockIdx.x * 64 + wid * 16;
    const int i = rowBase / NN, j0 = rowBase - i * NN;
    const float* zr = z + (size_t)(rowBase + rl) * CZ + kc * 8;

    float s1 = 0.f, s2 = 0.f;
    short8v af[4];
    #pragma unroll
    for (int ks = 0; ks < 4; ks++) {
        float4 z0 = *(const float4*)(zr + ks * 32);
        float4 z1 = *(const float4*)(zr + ks * 32 + 4);
        float zz[8] = {z0.x, z0.y, z0.z, z0.w, z1.x, z1.y, z1.z, z1.w};
        short8v a;
        #pragma unroll
        for (int q = 0; q < 8; q++) {
            s1 += zz[q];
            s2 += zz[q] * zz[q];
            a[q] = (short)f2bf(zz[q]);
        }
        af[ks] = a;
    }
    s1 += __shfl_xor(s1, 16); s2 += __shfl_xor(s2, 16);
    s1 += __shfl_xor(s1, 32); s2 += __shfl_xor(s2, 32);
    if (kc == 0) { st[wid][rl][0] = s1; st[wid][rl][1] = s2; }

    f32x4 acc = {};
    #pragma unroll
    for (int ks = 0; ks < 4; ks++) {
        short8v b = *(const short8v*)&w2bf[rl * CZ + ks * 32 + kc * 8];
        acc = __builtin_amdgcn_mfma_f32_16x16x32_bf16(af[ks], b, acc, 0, 0, 0);
    }
    __syncthreads();

    const float Ah = consts[rl], Bh = consts[16 + rl];
    unsigned short pv[4];
    #pragma unroll
    for (int reg = 0; reg < 4; reg++) {
        int r = 4 * kc + reg;
        float S1 = st[wid][r][0], S2 = st[wid][r][1];
        float mu   = S1 * (1.0f / CZ);
        float var  = S2 * (1.0f / CZ) - mu * mu;
        float rstd = rsqrtf(var + 1e-5f);
        float b = rstd * acc[reg] - rstd * mu * Ah + Bh + mterm[j0 + r];
        pv[reg] = f2bf(b);
    }
    if (rl < 8) {
        ushort4v o4 = {pv[0], pv[1], pv[2], pv[3]};
        *(ushort4v*)&wbl[((size_t)rl * NN + i) * NN + j0 + 4 * kc] = o4;
    }
}

// ---------------- k3: softmax over j, bf16 in place on wbl[h][i][:] ----------------
__global__ __launch_bounds__(256) void k3_softmax(unsigned short* __restrict__ wbl)
{
    const int tid = threadIdx.x, wave = tid >> 6, lane = tid & 63;
    const int row = blockIdx.x * 4 + wave;   // = h*384 + i
    unsigned short* p = wbl + (size_t)row * NN;
    float x[6];
    float mx = -1e30f;
    #pragma unroll
    for (int e = 0; e < 6; e++) { x[e] = bf2f(p[lane + e * 64]); mx = fmaxf(mx, x[e]); }
    #pragma unroll
    for (int off = 32; off; off >>= 1) mx = fmaxf(mx, __shfl_xor(mx, off));
    float sum = 0.f;
    #pragma unroll
    for (int e = 0; e < 6; e++) { x[e] = expf(x[e] - mx); sum += x[e]; }
    #pragma unroll
    for (int off = 32; off; off >>= 1) sum += __shfl_xor(sum, off);
    float inv = 1.0f / sum;
    #pragma unroll
    for (int e = 0; e < 6; e++) p[lane + e * 64] = f2bf(x[e] * inv);
}

// ---------------- k4: per-h MFMA GEMM; operand-swapped -> packed 8B ob stores ----------------
__global__ __launch_bounds__(256) void k4_mfma(
    const unsigned short* __restrict__ wbf, const unsigned short* __restrict__ vT,
    unsigned short* __restrict__ ob)
{
    __shared__ unsigned short Al[128 * 32];
    __shared__ unsigned short Bl[128 * 32];
    const int tid  = threadIdx.x;
    const int wid  = tid >> 6, lane = tid & 63;
    const int wm   = wid >> 1, wn = wid & 1;
    const int h    = blockIdx.z;
    const int i0   = blockIdx.y * 128;
    const int n0   = blockIdx.x * 128;
    const unsigned short* Ag = wbf + (size_t)h * NN * NN;
    const unsigned short* Bg = vT  + (size_t)h * 8192 * NN;

    f32x4 acc[4][4] = {};

    const int lrow = lane >> 2, lchunk = lane & 3;
    for (int k0 = 0; k0 < NN; k0 += 32) {
        #pragma unroll
        for (int q = 0; q < 2; q++) {
            int issue = wid * 2 + q;
            int r = issue * 16 + lrow;
            gload_lds16(Ag + (size_t)(i0 + r) * NN + k0 + lchunk * 8,
                        (void*)((char*)Al + issue * 1024));
            gload_lds16(Bg + (size_t)(n0 + r) * NN + k0 + lchunk * 8,
                        (void*)((char*)Bl + issue * 1024));
        }
        __syncthreads();

        short8v a[4], b[4];
        #pragma unroll
        for (int mi = 0; mi < 4; mi++)
            a[mi] = *(const short8v*)&Al[(wm * 64 + mi * 16 + (lane & 15)) * 32 + (lane >> 4) * 8];
        #pragma unroll
        for (int ni = 0; ni < 4; ni++)
            b[ni] = *(const short8v*)&Bl[(wn * 64 + ni * 16 + (lane & 15)) * 32 + (lane >> 4) * 8];
        #pragma unroll
        for (int mi = 0; mi < 4; mi++)
            #pragma unroll
            for (int ni = 0; ni < 4; ni++)
                acc[mi][ni] = __builtin_amdgcn_mfma_f32_16x16x32_bf16(b[ni], a[mi], acc[mi][ni], 0, 0, 0);
        __syncthreads();
    }

    #pragma unroll
    for (int mi = 0; mi < 4; mi++) {
        const int i = i0 + wm * 64 + mi * 16 + (lane & 15);
        #pragma unroll
        for (int ni = 0; ni < 4; ni++) {
            const int sc0 = n0 + wn * 64 + ni * 16 + ((lane >> 4) << 2);
            const int s = sc0 >> 5, c0 = sc0 & 31;
            ushort4v o4;
            #pragma unroll
            for (int r = 0; r < 4; r++) o4[r] = f2bf(acc[mi][ni][r]);
            *(ushort4v*)&ob[((size_t)s * NN + i) * HC + (h << 5) + c0] = o4;
        }
    }
}

// ---------------- k5: out[98304,64] = (o .* g)[98304,256] @ w_out[256,64]  via MFMA ----------------
__global__ __launch_bounds__(256) void k5_mfma(
    const unsigned short* __restrict__ ob, const unsigned short* __restrict__ g,
    const float* __restrict__ w_out, float* __restrict__ out)
{
    __shared__ unsigned short WT[64 * 256];   // w_out^T bf16, swizzled: idx ^ ((c&7)<<3)
    const int tid = threadIdx.x, wid = tid >> 6, lane = tid & 63;
    #pragma unroll
    for (int e = 0; e < 16; e++) {
        int fidx = (tid + e * 256) * 4;
        float4 w4 = *(const float4*)&w_out[fidx];
        int k = fidx >> 6, c0 = fidx & 63;
        float wv[4] = {w4.x, w4.y, w4.z, w4.w};
        #pragma unroll
        for (int q = 0; q < 4; q++) {
            int c = c0 + q;
            WT[(((c << 8) + k)) ^ ((c & 7) << 3)] = f2bf(wv[q]);
        }
    }
    __syncthreads();

    const size_t rowbase = (size_t)blockIdx.x * 64 + wid * 16;
    const int arow = lane & 15, achunk = lane >> 4;
    const unsigned short* op = ob + (rowbase + arow) * HC + achunk * 8;
    const unsigned short* gp = g  + (rowbase + arow) * HC + achunk * 8;

    f32x4 acc[4] = {};
    #pragma unroll
    for (int ks = 0; ks < 8; ks++) {
        ushort8v o8 = *(const ushort8v*)(op + ks * 32);
        ushort8v g8 = *(const ushort8v*)(gp + ks * 32);
        short8v a;
        #pragma unroll
        for (int q = 0; q < 8; q++)
            a[q] = (short)f2bf(bf2f(o8[q]) * bf2f(g8[q]));
        #pragma unroll
        for (int nf = 0; nf < 4; nf++) {
            const int c = nf * 16 + arow;
            short8v b = *(const short8v*)&WT[(((c << 8) + ks * 32 + achunk * 8)) ^ ((c & 7) << 3)];
            acc[nf] = __builtin_amdgcn_mfma_f32_16x16x32_bf16(a, b, acc[nf], 0, 0, 0);
        }
    }
    #pragma unroll
    for (int nf = 0; nf < 4; nf++)
        #pragma unroll
        for (int r = 0; r < 4; r++)
            out[(rowbase + achunk * 4 + r) * CM + nf * 16 + arow] = acc[nf][r];
}

extern "C" void kernel_launch(void* const* d_in, const int* in_sizes, int n_in,
                              void* d_out, int out_size, void* d_ws, size_t ws_size,
                              hipStream_t stream)
{
    const float* m      = (const float*)d_in[0];
    const float* z      = (const float*)d_in[1];
    const unsigned int* mask_raw = (const unsigned int*)d_in[2];
    const float* ln_m_w = (const float*)d_in[3];
    const float* ln_m_b = (const float*)d_in[4];
    const float* ln_z_w = (const float*)d_in[5];
    const float* ln_z_b = (const float*)d_in[6];
    const float* w_v    = (const float*)d_in[7];
    const float* w_b    = (const float*)d_in[8];
    const float* w_g    = (const float*)d_in[9];
    const float* w_out  = (const float*)d_in[10];
    float* out = (float*)d_out;

    // ws layout
    float* mterm = (float*)d_ws;
    unsigned short* wbl = (unsigned short*)(mterm + 384);
    unsigned short* vT  = wbl + 1179648;
    unsigned short* g   = vT + NV;
    unsigned short* ob  = g + NV;
    unsigned short* BTg = ob + NV;             // [512][64]
    unsigned short* w2bf = BTg + 32768;        // [16][128]
    float* consts = (float*)(w2bf + 2048);     // [32]
    unsigned short* mln = ob;                  // alias: dead before k4 writes ob

    k_prep<<<130, 256, 0, stream>>>(mask_raw, ln_z_w, ln_z_b, w_b, w_v, w_g,
                                    mterm, w2bf, consts, BTg);
    k1n_ln<<<1536, 256, 0, stream>>>(m, ln_m_w, ln_m_b, mln);
    k1b_vg<<<1536, 512, 0, stream>>>(BTg, mln, vT, g);
    k2_mfma<<<2304, 256, 0, stream>>>(z, w2bf, consts, mterm, wbl);
    k3_softmax<<<768, 256, 0, stream>>>(wbl);
    k4_mfma<<<dim3(64, 3, 8), 256, 0, stream>>>(wbl, vT, ob);
    k5_mfma<<<1536, 256, 0, stream>>>(ob, g, w_out, out);
}

// Round 21
// 127.302 us; speedup vs baseline: 1.0566x; 1.0359x over previous
//
#include <hip/hip_runtime.h>
#include <math.h>

// MSAPairWeightedAveraging — round 20: LN(m) fused into the single-dispatch 8-wave k1b
// (k1n deleted, mln intermediate deleted, redundant A staging deleted).
// Load order: lnw/lnb -> m rows -> W gload_lds, so LN waits at vmcnt(8) with W in flight;
// lgkmcnt(0)+s_barrier for Al visibility; per-wave vmcnt(0) for own W. Downstream identical
// to round 19 -> absmax byte-identical.
// S=256, N=384, C_M=64, C_Z=128, C=32, H=8, H*C=256.
// ws: mterm f32[384] | wbl bf16[8,384,384] | vT bf16[8,8192,384] | g bf16[98304,256]
//     | ob bf16[98304,256] | BTg bf16[512,64] | w2bf bf16[16,128] | consts f32[32]

#define SS 256
#define NN 384
#define CM 64
#define CZ 128
#define HH 8
#define HC 256
#define NV 25165824   // S*N*HC

typedef __attribute__((ext_vector_type(8))) short short8v;
typedef __attribute__((ext_vector_type(8))) unsigned short ushort8v;
typedef __attribute__((ext_vector_type(4))) unsigned short ushort4v;
typedef __attribute__((ext_vector_type(4))) float f32x4;

static __device__ __forceinline__ float bf2f(unsigned short u) {
    union { unsigned int i; float f; } x; x.i = ((unsigned int)u) << 16; return x.f;
}
static __device__ __forceinline__ unsigned short f2bf(float f) {
    union { float f; unsigned int i; } x; x.f = f;
    unsigned int r = x.i + 0x7FFFu + ((x.i >> 16) & 1u);   // RNE
    return (unsigned short)(r >> 16);
}
static __device__ __forceinline__ void gload_lds16(const void* g, void* l) {
    __builtin_amdgcn_global_load_lds((const __attribute__((address_space(1))) void*)g,
                                     (__attribute__((address_space(3))) void*)l, 16, 0, 0);
}

// ---------------- k_prep: fused {mask decode | LN-fold w_b | transpose w_v/w_g} ----------------
__global__ __launch_bounds__(256) void k_prep(
    const unsigned int* __restrict__ mu, const float* __restrict__ lnzw,
    const float* __restrict__ lnzb, const float* __restrict__ w_b,
    const float* __restrict__ w_v, const float* __restrict__ w_g,
    float* __restrict__ mterm, unsigned short* __restrict__ w2bf,
    float* __restrict__ consts, unsigned short* __restrict__ BTg)
{
    const int b = blockIdx.x, tid = threadIdx.x;
    if (b == 0) {
        __shared__ int byteLayout;
        if (tid == 0) byteLayout = 0;
        __syncthreads();
        if (tid < 96) {
            unsigned int u = mu[tid];
            if (u != 0u && u != 1u && u != 0x3F800000u) atomicOr(&byteLayout, 1);
        }
        __syncthreads();
        for (int j = tid; j < 384; j += 256) {
            int val;
            if (byteLayout) val = ((const unsigned char*)mu)[j];
            else            val = (mu[j] != 0u);
            mterm[j] = val ? 0.0f : -1e9f;
        }
    } else if (b == 1) {
        __shared__ float pA[128][8], pB[128][8];
        const int c = tid & 127;
        if (tid < 128) {
            float lw = lnzw[c], lb = lnzb[c];
            float4 wb0 = *(const float4*)&w_b[c * 8];
            float4 wb1 = *(const float4*)&w_b[c * 8 + 4];
            float wv[8] = {wb0.x, wb0.y, wb0.z, wb0.w, wb1.x, wb1.y, wb1.z, wb1.w};
            #pragma unroll
            for (int h = 0; h < 8; h++) {
                w2bf[h * CZ + c]       = f2bf(lw * wv[h]);
                w2bf[(8 + h) * CZ + c] = 0;
                pA[c][h] = lw * wv[h];
                pB[c][h] = lb * wv[h];
            }
        }
        __syncthreads();
        if (tid < 8) {
            float A = 0.f, B = 0.f;
            for (int q = 0; q < 128; q++) { A += pA[q][tid]; B += pB[q][tid]; }
            consts[tid] = A; consts[16 + tid] = B;
            consts[8 + tid] = 0.f; consts[24 + tid] = 0.f;
        }
    } else {
        const int col = (b - 2) * 4 + (tid >> 6);
        const int k   = tid & 63;
        float w = (col < 256) ? w_v[k * 256 + col] : w_g[k * 256 + (col - 256)];
        BTg[col * 64 + (k ^ ((col & 7) << 3))] = f2bf(w);
    }
}

// ---------------- k1b: fused LN + 8-wave one-family-per-wave barrier-light GEMM ----------------
// grid 1536 x 512 threads. wave wid: fam = wid>>2 (0:v, 1:g), wq = wid&3 (64-col quarter).
// Wave: load lnw/lnb + its 8 m-rows -> issue 8 W gload_lds -> LN (waits vmcnt(8), W in
// flight) -> ds_write Al slice -> lgkmcnt(0)+s_barrier -> vmcnt(0) -> 32 MFMA -> epilogue.
__global__ __launch_bounds__(512) void k1b_vg(
    const unsigned short* __restrict__ BTg, const float* __restrict__ m,
    const float* __restrict__ lnw, const float* __restrict__ lnb,
    unsigned short* __restrict__ vT, unsigned short* __restrict__ gout)
{
    __shared__ unsigned short Wl[32768];  // [512 cols][64 k] swizzled; wave-partitioned (8KB/wave)
    __shared__ unsigned short Al[4096];   // [64 rows][64 k] swizzled; cooperative LN output
    const int tid = threadIdx.x, wid = tid >> 6, lane = tid & 63;
    const int rl = lane & 15, kc = lane >> 4;
    const int fam = wid >> 2, wq = wid & 3;
    const int rowBase = blockIdx.x * 64;       // 64 | 384 -> never straddles s
    const int s = rowBase / NN, j0 = rowBase - s * NN;

    // 1) oldest in vmcnt queue: LN params, then this wave's 8 m-rows
    const float lw = lnw[lane], lb = lnb[lane];
    float mx[8];
    #pragma unroll
    for (int rr = 0; rr < 8; rr++)
        mx[rr] = m[(size_t)(rowBase + wid * 8 + rr) * CM + lane];
    __builtin_amdgcn_sched_barrier(0);

    // 2) newest: wave-private W staging (stays in flight under LN)
    #pragma unroll
    for (int it = 0; it < 8; it++) {
        int eoff = wid * 4096 + it * 512;          // == (fam*16384 + wq*4096) + it*512
        gload_lds16(BTg + eoff + lane * 8, (void*)((char*)Wl + eoff * 2));
    }
    __builtin_amdgcn_sched_barrier(0);

    // 3) LN of this wave's 8 rows -> Al (consumes mx at vmcnt(8))
    #pragma unroll
    for (int rr = 0; rr < 8; rr++) {
        int row = wid * 8 + rr;
        float x = mx[rr];
        float s1 = x, s2 = x * x;
        #pragma unroll
        for (int off = 32; off; off >>= 1) {
            s1 += __shfl_xor(s1, off);
            s2 += __shfl_xor(s2, off);
        }
        float mu  = s1 * (1.0f / CM);
        float var = s2 * (1.0f / CM) - mu * mu;
        float y = (x - mu) * rsqrtf(var + 1e-5f) * lw + lb;
        Al[row * 64 + (lane ^ ((row & 7) << 3))] = f2bf(y);
    }

    // 4) Al visibility: own ds_writes drained, then block barrier (vmcnt NOT drained)
    asm volatile("s_waitcnt lgkmcnt(0)" ::: "memory");
    __builtin_amdgcn_s_barrier();
    __builtin_amdgcn_sched_barrier(0);
    // 5) this wave's W staging complete
    asm volatile("s_waitcnt vmcnt(0)" ::: "memory");
    __builtin_amdgcn_sched_barrier(0);

    // A fragments
    short8v al[2][4];
    #pragma unroll
    for (int ks = 0; ks < 2; ks++)
        #pragma unroll
        for (int q = 0; q < 4; q++) {
            int row = q * 16 + rl;
            al[ks][q] = *(const short8v*)&Al[(row * 64 + ks * 32 + kc * 8) ^ ((row & 7) << 3)];
        }

    unsigned short* WP = Wl + wid * 4096;   // this wave's 8KB W region (cols local 0..63)
    unsigned short* VS = WP;                // reused as wave-private scratch after wf reads

    f32x4 acc[4][4] = {};
    if (fam == 0) {
        // v: A=al so j lands in reg dim
        #pragma unroll
        for (int ks = 0; ks < 2; ks++) {
            short8v wf[4];
            #pragma unroll
            for (int q = 0; q < 4; q++) {
                int cl = q * 16 + rl;   // local col; global col = wq*64+cl, (col&7)==(cl&7)
                wf[q] = *(const short8v*)&WP[(cl * 64 + ks * 32 + kc * 8) ^ ((cl & 7) << 3)];
            }
            #pragma unroll
            for (int mi = 0; mi < 4; mi++)
                #pragma unroll
                for (int nf = 0; nf < 4; nf++)
                    acc[mi][nf] = __builtin_amdgcn_mfma_f32_16x16x32_bf16(al[ks][mi], wf[nf], acc[mi][nf], 0, 0, 0);
        }
        #pragma unroll
        for (int mi = 0; mi < 4; mi++) {
            const int jb = mi * 16 + kc * 4;
            #pragma unroll
            for (int nf = 0; nf < 4; nf++) {
                int hcl = nf * 16 + rl;
                ushort4v o4;
                #pragma unroll
                for (int r = 0; r < 4; r++) o4[r] = f2bf(acc[mi][nf][r]);
                *(ushort4v*)&VS[(hcl * 64 + jb) ^ ((hcl & 7) << 3)] = o4;
            }
        }
        #pragma unroll
        for (int p = 0; p < 8; p++) {
            int hcl = p * 8 + (lane >> 3);
            int j8  = (lane & 7) * 8;
            ushort8v val = *(const ushort8v*)&VS[(hcl * 64 + j8) ^ ((hcl & 7) << 3)];
            int hc = wq * 64 + hcl;
            size_t vrow = (size_t)((hc >> 5) * 8192 + s * 32 + (hc & 31));
            *(ushort8v*)&vT[vrow * NN + j0 + j8] = val;
        }
    } else {
        // g: A=wf so hc lands in reg dim
        #pragma unroll
        for (int ks = 0; ks < 2; ks++) {
            short8v wf[4];
            #pragma unroll
            for (int q = 0; q < 4; q++) {
                int cl = q * 16 + rl;
                wf[q] = *(const short8v*)&WP[(cl * 64 + ks * 32 + kc * 8) ^ ((cl & 7) << 3)];
            }
            #pragma unroll
            for (int mi = 0; mi < 4; mi++)
                #pragma unroll
                for (int nf = 0; nf < 4; nf++)
                    acc[mi][nf] = __builtin_amdgcn_mfma_f32_16x16x32_bf16(wf[mi], al[ks][nf], acc[mi][nf], 0, 0, 0);
        }
        #pragma unroll
        for (int mi = 0; mi < 4; mi++) {
            const int hcb = mi * 16 + kc * 4;   // local hc 0..63
            #pragma unroll
            for (int nf = 0; nf < 4; nf++) {
                int rowl = nf * 16 + rl;
                ushort4v o4;
                #pragma unroll
                for (int r = 0; r < 4; r++)
                    o4[r] = f2bf(1.0f / (1.0f + __expf(-acc[mi][nf][r])));
                *(ushort4v*)&VS[(rowl * 64 + hcb) ^ ((rowl & 7) << 3)] = o4;
            }
        }
        #pragma unroll
        for (int p = 0; p < 8; p++) {
            int rowl = p * 8 + (lane >> 3);
            int hc8  = (lane & 7) * 8;
            ushort8v val = *(const ushort8v*)&VS[(rowl * 64 + hc8) ^ ((rowl & 7) << 3)];
            *(ushort8v*)&gout[(size_t)(rowBase + rowl) * HC + wq * 64 + hc8] = val;
        }
    }
}

// ---------------- k2: MFMA projection: b = rstd*(z@W2) - rstd*mu*A + B + mask ----------------
__global__ __launch_bounds__(256) void k2_mfma(
    const float* __restrict__ z, const unsigned short* __restrict__ w2bf,
    const float* __restrict__ consts, const float* __restrict__ mterm,
    unsigned short* __restrict__ wbl)
{
    __shared__ float st[4][16][2];
    const int tid = threadIdx.x, wid = tid >> 6, lane = tid & 63;
    const int rl = lane & 15, kc = lane >> 4;
    const int rowBase = blockIdx.x * 64 + wid * 16;
    const int i = rowBase / NN, j0 = rowBase - i * NN;
    const float* zr = z + (size_t)(rowBase + rl) * CZ + kc * 8;

    float s1 = 0.f, s2 = 0.f;
    short8v af[4];
    #pragma unroll
    for (int ks = 0; ks < 4; ks++) {
        float4 z0 = *(const float4*)(zr + ks * 32);
        float4 z1 = *(const float4*)(zr + ks * 32 + 4);
        float zz[8] = {z0.x, z0.y, z0.z, z0.w, z1.x, z1.y, z1.z, z1.w};
        short8v a;
        #pragma unroll
        for (int q = 0; q < 8; q++) {
            s1 += zz[q];
            s2 += zz[q] * zz[q];
            a[q] = (short)f2bf(zz[q]);
        }
        af[ks] = a;
    }
    s1 += __shfl_xor(s1, 16); s2 += __shfl_xor(s2, 16);
    s1 += __shfl_xor(s1, 32); s2 += __shfl_xor(s2, 32);
    if (kc == 0) { st[wid][rl][0] = s1; st[wid][rl][1] = s2; }

    f32x4 acc = {};
    #pragma unroll
    for (int ks = 0; ks < 4; ks++) {
        short8v b = *(const short8v*)&w2bf[rl * CZ + ks * 32 + kc * 8];
        acc = __builtin_amdgcn_mfma_f32_16x16x32_bf16(af[ks], b, acc, 0, 0, 0);
    }
    __syncthreads();

    const float Ah = consts[rl], Bh = consts[16 + rl];
    unsigned short pv[4];
    #pragma unroll
    for (int reg = 0; reg < 4; reg++) {
        int r = 4 * kc + reg;
        float S1 = st[wid][r][0], S2 = st[wid][r][1];
        float mu   = S1 * (1.0f / CZ);
        float var  = S2 * (1.0f / CZ) - mu * mu;
        float rstd = rsqrtf(var + 1e-5f);
        float b = rstd * acc[reg] - rstd * mu * Ah + Bh + mterm[j0 + r];
        pv[reg] = f2bf(b);
    }
    if (rl < 8) {
        ushort4v o4 = {pv[0], pv[1], pv[2], pv[3]};
        *(ushort4v*)&wbl[((size_t)rl * NN + i) * NN + j0 + 4 * kc] = o4;
    }
}

// ---------------- k3: softmax over j, bf16 in place on wbl[h][i][:] ----------------
__global__ __launch_bounds__(256) void k3_softmax(unsigned short* __restrict__ wbl)
{
    const int tid = threadIdx.x, wave = tid >> 6, lane = tid & 63;
    const int row = blockIdx.x * 4 + wave;   // = h*384 + i
    unsigned short* p = wbl + (size_t)row * NN;
    float x[6];
    float mx = -1e30f;
    #pragma unroll
    for (int e = 0; e < 6; e++) { x[e] = bf2f(p[lane + e * 64]); mx = fmaxf(mx, x[e]); }
    #pragma unroll
    for (int off = 32; off; off >>= 1) mx = fmaxf(mx, __shfl_xor(mx, off));
    float sum = 0.f;
    #pragma unroll
    for (int e = 0; e < 6; e++) { x[e] = expf(x[e] - mx); sum += x[e]; }
    #pragma unroll
    for (int off = 32; off; off >>= 1) sum += __shfl_xor(sum, off);
    float inv = 1.0f / sum;
    #pragma unroll
    for (int e = 0; e < 6; e++) p[lane + e * 64] = f2bf(x[e] * inv);
}

// ---------------- k4: per-h MFMA GEMM; operand-swapped -> packed 8B ob stores ----------------
__global__ __launch_bounds__(256) void k4_mfma(
    const unsigned short* __restrict__ wbf, const unsigned short* __restrict__ vT,
    unsigned short* __restrict__ ob)
{
    __shared__ unsigned short Al[128 * 32];
    __shared__ unsigned short Bl[128 * 32];
    const int tid  = threadIdx.x;
    const int wid  = tid >> 6, lane = tid & 63;
    const int wm   = wid >> 1, wn = wid & 1;
    const int h    = blockIdx.z;
    const int i0   = blockIdx.y * 128;
    const int n0   = blockIdx.x * 128;
    const unsigned short* Ag = wbf + (size_t)h * NN * NN;
    const unsigned short* Bg = vT  + (size_t)h * 8192 * NN;

    f32x4 acc[4][4] = {};

    const int lrow = lane >> 2, lchunk = lane & 3;
    for (int k0 = 0; k0 < NN; k0 += 32) {
        #pragma unroll
        for (int q = 0; q < 2; q++) {
            int issue = wid * 2 + q;
            int r = issue * 16 + lrow;
            gload_lds16(Ag + (size_t)(i0 + r) * NN + k0 + lchunk * 8,
                        (void*)((char*)Al + issue * 1024));
            gload_lds16(Bg + (size_t)(n0 + r) * NN + k0 + lchunk * 8,
                        (void*)((char*)Bl + issue * 1024));
        }
        __syncthreads();

        short8v a[4], b[4];
        #pragma unroll
        for (int mi = 0; mi < 4; mi++)
            a[mi] = *(const short8v*)&Al[(wm * 64 + mi * 16 + (lane & 15)) * 32 + (lane >> 4) * 8];
        #pragma unroll
        for (int ni = 0; ni < 4; ni++)
            b[ni] = *(const short8v*)&Bl[(wn * 64 + ni * 16 + (lane & 15)) * 32 + (lane >> 4) * 8];
        #pragma unroll
        for (int mi = 0; mi < 4; mi++)
            #pragma unroll
            for (int ni = 0; ni < 4; ni++)
                acc[mi][ni] = __builtin_amdgcn_mfma_f32_16x16x32_bf16(b[ni], a[mi], acc[mi][ni], 0, 0, 0);
        __syncthreads();
    }

    #pragma unroll
    for (int mi = 0; mi < 4; mi++) {
        const int i = i0 + wm * 64 + mi * 16 + (lane & 15);
        #pragma unroll
        for (int ni = 0; ni < 4; ni++) {
            const int sc0 = n0 + wn * 64 + ni * 16 + ((lane >> 4) << 2);
            const int s = sc0 >> 5, c0 = sc0 & 31;
            ushort4v o4;
            #pragma unroll
            for (int r = 0; r < 4; r++) o4[r] = f2bf(acc[mi][ni][r]);
            *(ushort4v*)&ob[((size_t)s * NN + i) * HC + (h << 5) + c0] = o4;
        }
    }
}

// ---------------- k5: out[98304,64] = (o .* g)[98304,256] @ w_out[256,64]  via MFMA ----------------
__global__ __launch_bounds__(256) void k5_mfma(
    const unsigned short* __restrict__ ob, const unsigned short* __restrict__ g,
    const float* __restrict__ w_out, float* __restrict__ out)
{
    __shared__ unsigned short WT[64 * 256];   // w_out^T bf16, swizzled: idx ^ ((c&7)<<3)
    const int tid = threadIdx.x, wid = tid >> 6, lane = tid & 63;
    #pragma unroll
    for (int e = 0; e < 16; e++) {
        int fidx = (tid + e * 256) * 4;
        float4 w4 = *(const float4*)&w_out[fidx];
        int k = fidx >> 6, c0 = fidx & 63;
        float wv[4] = {w4.x, w4.y, w4.z, w4.w};
        #pragma unroll
        for (int q = 0; q < 4; q++) {
            int c = c0 + q;
            WT[(((c << 8) + k)) ^ ((c & 7) << 3)] = f2bf(wv[q]);
        }
    }
    __syncthreads();

    const size_t rowbase = (size_t)blockIdx.x * 64 + wid * 16;
    const int arow = lane & 15, achunk = lane >> 4;
    const unsigned short* op = ob + (rowbase + arow) * HC + achunk * 8;
    const unsigned short* gp = g  + (rowbase + arow) * HC + achunk * 8;

    f32x4 acc[4] = {};
    #pragma unroll
    for (int ks = 0; ks < 8; ks++) {
        ushort8v o8 = *(const ushort8v*)(op + ks * 32);
        ushort8v g8 = *(const ushort8v*)(gp + ks * 32);
        short8v a;
        #pragma unroll
        for (int q = 0; q < 8; q++)
            a[q] = (short)f2bf(bf2f(o8[q]) * bf2f(g8[q]));
        #pragma unroll
        for (int nf = 0; nf < 4; nf++) {
            const int c = nf * 16 + arow;
            short8v b = *(const short8v*)&WT[(((c << 8) + ks * 32 + achunk * 8)) ^ ((c & 7) << 3)];
            acc[nf] = __builtin_amdgcn_mfma_f32_16x16x32_bf16(a, b, acc[nf], 0, 0, 0);
        }
    }
    #pragma unroll
    for (int nf = 0; nf < 4; nf++)
        #pragma unroll
        for (int r = 0; r < 4; r++)
            out[(rowbase + achunk * 4 + r) * CM + nf * 16 + arow] = acc[nf][r];
}

extern "C" void kernel_launch(void* const* d_in, const int* in_sizes, int n_in,
                              void* d_out, int out_size, void* d_ws, size_t ws_size,
                              hipStream_t stream)
{
    const float* m      = (const float*)d_in[0];
    const float* z      = (const float*)d_in[1];
    const unsigned int* mask_raw = (const unsigned int*)d_in[2];
    const float* ln_m_w = (const float*)d_in[3];
    const float* ln_m_b = (const float*)d_in[4];
    const float* ln_z_w = (const float*)d_in[5];
    const float* ln_z_b = (const float*)d_in[6];
    const float* w_v    = (const float*)d_in[7];
    const float* w_b    = (const float*)d_in[8];
    const float* w_g    = (const float*)d_in[9];
    const float* w_out  = (const float*)d_in[10];
    float* out = (float*)d_out;

    // ws layout
    float* mterm = (float*)d_ws;
    unsigned short* wbl = (unsigned short*)(mterm + 384);
    unsigned short* vT  = wbl + 1179648;
    unsigned short* g   = vT + NV;
    unsigned short* ob  = g + NV;
    unsigned short* BTg = ob + NV;             // [512][64]
    unsigned short* w2bf = BTg + 32768;        // [16][128]
    float* consts = (float*)(w2bf + 2048);     // [32]

    k_prep<<<130, 256, 0, stream>>>(mask_raw, ln_z_w, ln_z_b, w_b, w_v, w_g,
                                    mterm, w2bf, consts, BTg);
    k1b_vg<<<1536, 512, 0, stream>>>(BTg, m, ln_m_w, ln_m_b, vT, g);
    k2_mfma<<<2304, 256, 0, stream>>>(z, w2bf, consts, mterm, wbl);
    k3_softmax<<<768, 256, 0, stream>>>(wbl);
    k4_mfma<<<dim3(64, 3, 8), 256, 0, stream>>>(wbl, vT, ob);
    k5_mfma<<<1536, 256, 0, stream>>>(ob, g, w_out, out);
}

// Round 22
// 124.594 us; speedup vs baseline: 1.0795x; 1.0217x over previous
//
#include <hip/hip_runtime.h>
#include <math.h>

// MSAPairWeightedAveraging — round 21: k2+k3 fused into k23 (block per i, 8 waves:
// 3x k2-chunk per wave -> logits in padded LDS -> in-block softmax, wave w = head w).
// Stats via __shfl (no LDS/barrier in the chunk phase). Bytes identical to k2->k3.
// S=256, N=384, C_M=64, C_Z=128, C=32, H=8, H*C=256.
// ws: mterm f32[384] | wbl bf16[8,384,384] | vT bf16[8,8192,384] | g bf16[98304,256]
//     | ob bf16[98304,256] | BTg bf16[512,64] | w2bf bf16[16,128] | consts f32[32]

#define SS 256
#define NN 384
#define CM 64
#define CZ 128
#define HH 8
#define HC 256
#define NV 25165824   // S*N*HC

typedef __attribute__((ext_vector_type(8))) short short8v;
typedef __attribute__((ext_vector_type(8))) unsigned short ushort8v;
typedef __attribute__((ext_vector_type(4))) unsigned short ushort4v;
typedef __attribute__((ext_vector_type(4))) float f32x4;

static __device__ __forceinline__ float bf2f(unsigned short u) {
    union { unsigned int i; float f; } x; x.i = ((unsigned int)u) << 16; return x.f;
}
static __device__ __forceinline__ unsigned short f2bf(float f) {
    union { float f; unsigned int i; } x; x.f = f;
    unsigned int r = x.i + 0x7FFFu + ((x.i >> 16) & 1u);   // RNE
    return (unsigned short)(r >> 16);
}
static __device__ __forceinline__ void gload_lds16(const void* g, void* l) {
    __builtin_amdgcn_global_load_lds((const __attribute__((address_space(1))) void*)g,
                                     (__attribute__((address_space(3))) void*)l, 16, 0, 0);
}

// ---------------- k_prep: fused {mask decode | LN-fold w_b | transpose w_v/w_g} ----------------
__global__ __launch_bounds__(256) void k_prep(
    const unsigned int* __restrict__ mu, const float* __restrict__ lnzw,
    const float* __restrict__ lnzb, const float* __restrict__ w_b,
    const float* __restrict__ w_v, const float* __restrict__ w_g,
    float* __restrict__ mterm, unsigned short* __restrict__ w2bf,
    float* __restrict__ consts, unsigned short* __restrict__ BTg)
{
    const int b = blockIdx.x, tid = threadIdx.x;
    if (b == 0) {
        __shared__ int byteLayout;
        if (tid == 0) byteLayout = 0;
        __syncthreads();
        if (tid < 96) {
            unsigned int u = mu[tid];
            if (u != 0u && u != 1u && u != 0x3F800000u) atomicOr(&byteLayout, 1);
        }
        __syncthreads();
        for (int j = tid; j < 384; j += 256) {
            int val;
            if (byteLayout) val = ((const unsigned char*)mu)[j];
            else            val = (mu[j] != 0u);
            mterm[j] = val ? 0.0f : -1e9f;
        }
    } else if (b == 1) {
        __shared__ float pA[128][8], pB[128][8];
        const int c = tid & 127;
        if (tid < 128) {
            float lw = lnzw[c], lb = lnzb[c];
            float4 wb0 = *(const float4*)&w_b[c * 8];
            float4 wb1 = *(const float4*)&w_b[c * 8 + 4];
            float wv[8] = {wb0.x, wb0.y, wb0.z, wb0.w, wb1.x, wb1.y, wb1.z, wb1.w};
            #pragma unroll
            for (int h = 0; h < 8; h++) {
                w2bf[h * CZ + c]       = f2bf(lw * wv[h]);
                w2bf[(8 + h) * CZ + c] = 0;
                pA[c][h] = lw * wv[h];
                pB[c][h] = lb * wv[h];
            }
        }
        __syncthreads();
        if (tid < 8) {
            float A = 0.f, B = 0.f;
            for (int q = 0; q < 128; q++) { A += pA[q][tid]; B += pB[q][tid]; }
            consts[tid] = A; consts[16 + tid] = B;
            consts[8 + tid] = 0.f; consts[24 + tid] = 0.f;
        }
    } else {
        const int col = (b - 2) * 4 + (tid >> 6);
        const int k   = tid & 63;
        float w = (col < 256) ? w_v[k * 256 + col] : w_g[k * 256 + (col - 256)];
        BTg[col * 64 + (k ^ ((col & 7) << 3))] = f2bf(w);
    }
}

// ---------------- k1b: fused LN + 8-wave one-family-per-wave barrier-light GEMM ----------------
__global__ __launch_bounds__(512) void k1b_vg(
    const unsigned short* __restrict__ BTg, const float* __restrict__ m,
    const float* __restrict__ lnw, const float* __restrict__ lnb,
    unsigned short* __restrict__ vT, unsigned short* __restrict__ gout)
{
    __shared__ unsigned short Wl[32768];  // [512 cols][64 k] swizzled; wave-partitioned (8KB/wave)
    __shared__ unsigned short Al[4096];   // [64 rows][64 k] swizzled; cooperative LN output
    const int tid = threadIdx.x, wid = tid >> 6, lane = tid & 63;
    const int rl = lane & 15, kc = lane >> 4;
    const int fam = wid >> 2, wq = wid & 3;
    const int rowBase = blockIdx.x * 64;       // 64 | 384 -> never straddles s
    const int s = rowBase / NN, j0 = rowBase - s * NN;

    // 1) oldest in vmcnt queue: LN params, then this wave's 8 m-rows
    const float lw = lnw[lane], lb = lnb[lane];
    float mx[8];
    #pragma unroll
    for (int rr = 0; rr < 8; rr++)
        mx[rr] = m[(size_t)(rowBase + wid * 8 + rr) * CM + lane];
    __builtin_amdgcn_sched_barrier(0);

    // 2) newest: wave-private W staging (stays in flight under LN)
    #pragma unroll
    for (int it = 0; it < 8; it++) {
        int eoff = wid * 4096 + it * 512;          // == (fam*16384 + wq*4096) + it*512
        gload_lds16(BTg + eoff + lane * 8, (void*)((char*)Wl + eoff * 2));
    }
    __builtin_amdgcn_sched_barrier(0);

    // 3) LN of this wave's 8 rows -> Al (consumes mx at vmcnt(8))
    #pragma unroll
    for (int rr = 0; rr < 8; rr++) {
        int row = wid * 8 + rr;
        float x = mx[rr];
        float s1 = x, s2 = x * x;
        #pragma unroll
        for (int off = 32; off; off >>= 1) {
            s1 += __shfl_xor(s1, off);
            s2 += __shfl_xor(s2, off);
        }
        float mu  = s1 * (1.0f / CM);
        float var = s2 * (1.0f / CM) - mu * mu;
        float y = (x - mu) * rsqrtf(var + 1e-5f) * lw + lb;
        Al[row * 64 + (lane ^ ((row & 7) << 3))] = f2bf(y);
    }

    // 4) Al visibility: own ds_writes drained, then block barrier (vmcnt NOT drained)
    asm volatile("s_waitcnt lgkmcnt(0)" ::: "memory");
    __builtin_amdgcn_s_barrier();
    __builtin_amdgcn_sched_barrier(0);
    // 5) this wave's W staging complete
    asm volatile("s_waitcnt vmcnt(0)" ::: "memory");
    __builtin_amdgcn_sched_barrier(0);

    // A fragments
    short8v al[2][4];
    #pragma unroll
    for (int ks = 0; ks < 2; ks++)
        #pragma unroll
        for (int q = 0; q < 4; q++) {
            int row = q * 16 + rl;
            al[ks][q] = *(const short8v*)&Al[(row * 64 + ks * 32 + kc * 8) ^ ((row & 7) << 3)];
        }

    unsigned short* WP = Wl + wid * 4096;   // this wave's 8KB W region (cols local 0..63)
    unsigned short* VS = WP;                // reused as wave-private scratch after wf reads

    f32x4 acc[4][4] = {};
    if (fam == 0) {
        // v: A=al so j lands in reg dim
        #pragma unroll
        for (int ks = 0; ks < 2; ks++) {
            short8v wf[4];
            #pragma unroll
            for (int q = 0; q < 4; q++) {
                int cl = q * 16 + rl;   // local col; global col = wq*64+cl, (col&7)==(cl&7)
                wf[q] = *(const short8v*)&WP[(cl * 64 + ks * 32 + kc * 8) ^ ((cl & 7) << 3)];
            }
            #pragma unroll
            for (int mi = 0; mi < 4; mi++)
                #pragma unroll
                for (int nf = 0; nf < 4; nf++)
                    acc[mi][nf] = __builtin_amdgcn_mfma_f32_16x16x32_bf16(al[ks][mi], wf[nf], acc[mi][nf], 0, 0, 0);
        }
        #pragma unroll
        for (int mi = 0; mi < 4; mi++) {
            const int jb = mi * 16 + kc * 4;
            #pragma unroll
            for (int nf = 0; nf < 4; nf++) {
                int hcl = nf * 16 + rl;
                ushort4v o4;
                #pragma unroll
                for (int r = 0; r < 4; r++) o4[r] = f2bf(acc[mi][nf][r]);
                *(ushort4v*)&VS[(hcl * 64 + jb) ^ ((hcl & 7) << 3)] = o4;
            }
        }
        #pragma unroll
        for (int p = 0; p < 8; p++) {
            int hcl = p * 8 + (lane >> 3);
            int j8  = (lane & 7) * 8;
            ushort8v val = *(const ushort8v*)&VS[(hcl * 64 + j8) ^ ((hcl & 7) << 3)];
            int hc = wq * 64 + hcl;
            size_t vrow = (size_t)((hc >> 5) * 8192 + s * 32 + (hc & 31));
            *(ushort8v*)&vT[vrow * NN + j0 + j8] = val;
        }
    } else {
        // g: A=wf so hc lands in reg dim
        #pragma unroll
        for (int ks = 0; ks < 2; ks++) {
            short8v wf[4];
            #pragma unroll
            for (int q = 0; q < 4; q++) {
                int cl = q * 16 + rl;
                wf[q] = *(const short8v*)&WP[(cl * 64 + ks * 32 + kc * 8) ^ ((cl & 7) << 3)];
            }
            #pragma unroll
            for (int mi = 0; mi < 4; mi++)
                #pragma unroll
                for (int nf = 0; nf < 4; nf++)
                    acc[mi][nf] = __builtin_amdgcn_mfma_f32_16x16x32_bf16(wf[mi], al[ks][nf], acc[mi][nf], 0, 0, 0);
        }
        #pragma unroll
        for (int mi = 0; mi < 4; mi++) {
            const int hcb = mi * 16 + kc * 4;   // local hc 0..63
            #pragma unroll
            for (int nf = 0; nf < 4; nf++) {
                int rowl = nf * 16 + rl;
                ushort4v o4;
                #pragma unroll
                for (int r = 0; r < 4; r++)
                    o4[r] = f2bf(1.0f / (1.0f + __expf(-acc[mi][nf][r])));
                *(ushort4v*)&VS[(rowl * 64 + hcb) ^ ((rowl & 7) << 3)] = o4;
            }
        }
        #pragma unroll
        for (int p = 0; p < 8; p++) {
            int rowl = p * 8 + (lane >> 3);
            int hc8  = (lane & 7) * 8;
            ushort8v val = *(const ushort8v*)&VS[(rowl * 64 + hc8) ^ ((rowl & 7) << 3)];
            *(ushort8v*)&gout[(size_t)(rowBase + rowl) * HC + wq * 64 + hc8] = val;
        }
    }
}

// ---------------- k23: fused LN(z)@W2 projection + mask + softmax, block per i ----------------
// 8 waves; wave handles rows j = wid*48 + ch*16 + rl over 3 chunks (k2's exact chunk math,
// stats via __shfl); logits -> Llog[384][10] bf16 (pad 10 -> conflict-free softmax reads);
// barrier; wave w softmaxes h=w over all 384 j (k3's exact ops/stores).
__global__ __launch_bounds__(512) void k23_lnz_softmax(
    const float* __restrict__ z, const unsigned short* __restrict__ w2bf,
    const float* __restrict__ consts, const float* __restrict__ mterm,
    unsigned short* __restrict__ wbl)
{
    __shared__ unsigned short Llog[384 * 10];   // [j][h] padded, 7.5 KB
    const int tid = threadIdx.x, wid = tid >> 6, lane = tid & 63;
    const int rl = lane & 15, kc = lane >> 4;
    const int i = blockIdx.x;

    // hoisted B fragments (identical bytes each chunk)
    short8v bf[4];
    #pragma unroll
    for (int ks = 0; ks < 4; ks++)
        bf[ks] = *(const short8v*)&w2bf[rl * CZ + ks * 32 + kc * 8];
    const float Ah = consts[rl], Bh = consts[16 + rl];

    #pragma unroll
    for (int ch = 0; ch < 3; ch++) {
        const int jb = wid * 48 + ch * 16;
        const float* zr = z + ((size_t)i * NN + jb + rl) * CZ + kc * 8;

        float s1 = 0.f, s2 = 0.f;
        short8v af[4];
        #pragma unroll
        for (int ks = 0; ks < 4; ks++) {
            float4 z0 = *(const float4*)(zr + ks * 32);
            float4 z1 = *(const float4*)(zr + ks * 32 + 4);
            float zz[8] = {z0.x, z0.y, z0.z, z0.w, z1.x, z1.y, z1.z, z1.w};
            short8v a;
            #pragma unroll
            for (int q = 0; q < 8; q++) {
                s1 += zz[q];
                s2 += zz[q] * zz[q];
                a[q] = (short)f2bf(zz[q]);
            }
            af[ks] = a;
        }
        s1 += __shfl_xor(s1, 16); s2 += __shfl_xor(s2, 16);
        s1 += __shfl_xor(s1, 32); s2 += __shfl_xor(s2, 32);
        // lane l now holds full stats of row (l&15)

        f32x4 acc = {};
        #pragma unroll
        for (int ks = 0; ks < 4; ks++)
            acc = __builtin_amdgcn_mfma_f32_16x16x32_bf16(af[ks], bf[ks], acc, 0, 0, 0);

        unsigned short pv[4];
        #pragma unroll
        for (int reg = 0; reg < 4; reg++) {
            int r = 4 * kc + reg;
            float S1 = __shfl(s1, r);
            float S2 = __shfl(s2, r);
            float mu   = S1 * (1.0f / CZ);
            float var  = S2 * (1.0f / CZ) - mu * mu;
            float rstd = rsqrtf(var + 1e-5f);
            float b = rstd * acc[reg] - rstd * mu * Ah + Bh + mterm[jb + r];
            pv[reg] = f2bf(b);
        }
        if (rl < 8) {
            #pragma unroll
            for (int reg = 0; reg < 4; reg++)
                Llog[(jb + 4 * kc + reg) * 10 + rl] = pv[reg];
        }
    }
    __syncthreads();

    // softmax: wave wid = head wid, over j = lane + e*64
    unsigned short* p = wbl + ((size_t)wid * NN + i) * NN;
    float x[6];
    float mx = -1e30f;
    #pragma unroll
    for (int e = 0; e < 6; e++) { x[e] = bf2f(Llog[(lane + e * 64) * 10 + wid]); mx = fmaxf(mx, x[e]); }
    #pragma unroll
    for (int off = 32; off; off >>= 1) mx = fmaxf(mx, __shfl_xor(mx, off));
    float sum = 0.f;
    #pragma unroll
    for (int e = 0; e < 6; e++) { x[e] = expf(x[e] - mx); sum += x[e]; }
    #pragma unroll
    for (int off = 32; off; off >>= 1) sum += __shfl_xor(sum, off);
    float inv = 1.0f / sum;
    #pragma unroll
    for (int e = 0; e < 6; e++) p[lane + e * 64] = f2bf(x[e] * inv);
}

// ---------------- k4: per-h MFMA GEMM; operand-swapped -> packed 8B ob stores ----------------
__global__ __launch_bounds__(256) void k4_mfma(
    const unsigned short* __restrict__ wbf, const unsigned short* __restrict__ vT,
    unsigned short* __restrict__ ob)
{
    __shared__ unsigned short Al[128 * 32];
    __shared__ unsigned short Bl[128 * 32];
    const int tid  = threadIdx.x;
    const int wid  = tid >> 6, lane = tid & 63;
    const int wm   = wid >> 1, wn = wid & 1;
    const int h    = blockIdx.z;
    const int i0   = blockIdx.y * 128;
    const int n0   = blockIdx.x * 128;
    const unsigned short* Ag = wbf + (size_t)h * NN * NN;
    const unsigned short* Bg = vT  + (size_t)h * 8192 * NN;

    f32x4 acc[4][4] = {};

    const int lrow = lane >> 2, lchunk = lane & 3;
    for (int k0 = 0; k0 < NN; k0 += 32) {
        #pragma unroll
        for (int q = 0; q < 2; q++) {
            int issue = wid * 2 + q;
            int r = issue * 16 + lrow;
            gload_lds16(Ag + (size_t)(i0 + r) * NN + k0 + lchunk * 8,
                        (void*)((char*)Al + issue * 1024));
            gload_lds16(Bg + (size_t)(n0 + r) * NN + k0 + lchunk * 8,
                        (void*)((char*)Bl + issue * 1024));
        }
        __syncthreads();

        short8v a[4], b[4];
        #pragma unroll
        for (int mi = 0; mi < 4; mi++)
            a[mi] = *(const short8v*)&Al[(wm * 64 + mi * 16 + (lane & 15)) * 32 + (lane >> 4) * 8];
        #pragma unroll
        for (int ni = 0; ni < 4; ni++)
            b[ni] = *(const short8v*)&Bl[(wn * 64 + ni * 16 + (lane & 15)) * 32 + (lane >> 4) * 8];
        #pragma unroll
        for (int mi = 0; mi < 4; mi++)
            #pragma unroll
            for (int ni = 0; ni < 4; ni++)
                acc[mi][ni] = __builtin_amdgcn_mfma_f32_16x16x32_bf16(b[ni], a[mi], acc[mi][ni], 0, 0, 0);
        __syncthreads();
    }

    #pragma unroll
    for (int mi = 0; mi < 4; mi++) {
        const int i = i0 + wm * 64 + mi * 16 + (lane & 15);
        #pragma unroll
        for (int ni = 0; ni < 4; ni++) {
            const int sc0 = n0 + wn * 64 + ni * 16 + ((lane >> 4) << 2);
            const int s = sc0 >> 5, c0 = sc0 & 31;
            ushort4v o4;
            #pragma unroll
            for (int r = 0; r < 4; r++) o4[r] = f2bf(acc[mi][ni][r]);
            *(ushort4v*)&ob[((size_t)s * NN + i) * HC + (h << 5) + c0] = o4;
        }
    }
}

// ---------------- k5: out[98304,64] = (o .* g)[98304,256] @ w_out[256,64]  via MFMA ----------------
__global__ __launch_bounds__(256) void k5_mfma(
    const unsigned short* __restrict__ ob, const unsigned short* __restrict__ g,
    const float* __restrict__ w_out, float* __restrict__ out)
{
    __shared__ unsigned short WT[64 * 256];   // w_out^T bf16, swizzled: idx ^ ((c&7)<<3)
    const int tid = threadIdx.x, wid = tid >> 6, lane = tid & 63;
    #pragma unroll
    for (int e = 0; e < 16; e++) {
        int fidx = (tid + e * 256) * 4;
        float4 w4 = *(const float4*)&w_out[fidx];
        int k = fidx >> 6, c0 = fidx & 63;
        float wv[4] = {w4.x, w4.y, w4.z, w4.w};
        #pragma unroll
        for (int q = 0; q < 4; q++) {
            int c = c0 + q;
            WT[(((c << 8) + k)) ^ ((c & 7) << 3)] = f2bf(wv[q]);
        }
    }
    __syncthreads();

    const size_t rowbase = (size_t)blockIdx.x * 64 + wid * 16;
    const int arow = lane & 15, achunk = lane >> 4;
    const unsigned short* op = ob + (rowbase + arow) * HC + achunk * 8;
    const unsigned short* gp = g  + (rowbase + arow) * HC + achunk * 8;

    f32x4 acc[4] = {};
    #pragma unroll
    for (int ks = 0; ks < 8; ks++) {
        ushort8v o8 = *(const ushort8v*)(op + ks * 32);
        ushort8v g8 = *(const ushort8v*)(gp + ks * 32);
        short8v a;
        #pragma unroll
        for (int q = 0; q < 8; q++)
            a[q] = (short)f2bf(bf2f(o8[q]) * bf2f(g8[q]));
        #pragma unroll
        for (int nf = 0; nf < 4; nf++) {
            const int c = nf * 16 + arow;
            short8v b = *(const short8v*)&WT[(((c << 8) + ks * 32 + achunk * 8)) ^ ((c & 7) << 3)];
            acc[nf] = __builtin_amdgcn_mfma_f32_16x16x32_bf16(a, b, acc[nf], 0, 0, 0);
        }
    }
    #pragma unroll
    for (int nf = 0; nf < 4; nf++)
        #pragma unroll
        for (int r = 0; r < 4; r++)
            out[(rowbase + achunk * 4 + r) * CM + nf * 16 + arow] = acc[nf][r];
}

extern "C" void kernel_launch(void* const* d_in, const int* in_sizes, int n_in,
                              void* d_out, int out_size, void* d_ws, size_t ws_size,
                              hipStream_t stream)
{
    const float* m      = (const float*)d_in[0];
    const float* z      = (const float*)d_in[1];
    const unsigned int* mask_raw = (const unsigned int*)d_in[2];
    const float* ln_m_w = (const float*)d_in[3];
    const float* ln_m_b = (const float*)d_in[4];
    const float* ln_z_w = (const float*)d_in[5];
    const float* ln_z_b = (const float*)d_in[6];
    const float* w_v    = (const float*)d_in[7];
    const float* w_b    = (const float*)d_in[8];
    const float* w_g    = (const float*)d_in[9];
    const float* w_out  = (const float*)d_in[10];
    float* out = (float*)d_out;

    // ws layout
    float* mterm = (float*)d_ws;
    unsigned short* wbl = (unsigned short*)(mterm + 384);
    unsigned short* vT  = wbl + 1179648;
    unsigned short* g   = vT + NV;
    unsigned short* ob  = g + NV;
    unsigned short* BTg = ob + NV;             // [512][64]
    unsigned short* w2bf = BTg + 32768;        // [16][128]
    float* consts = (float*)(w2bf + 2048);     // [32]

    k_prep<<<130, 256, 0, stream>>>(mask_raw, ln_z_w, ln_z_b, w_b, w_v, w_g,
                                    mterm, w2bf, consts, BTg);
    k1b_vg<<<1536, 512, 0, stream>>>(BTg, m, ln_m_w, ln_m_b, vT, g);
    k23_lnz_softmax<<<384, 512, 0, stream>>>(z, w2bf, consts, mterm, wbl);
    k4_mfma<<<dim3(64, 3, 8), 256, 0, stream>>>(wbl, vT, ob);
    k5_mfma<<<1536, 256, 0, stream>>>(ob, g, w_out, out);
}

// Round 23
// 123.884 us; speedup vs baseline: 1.0857x; 1.0057x over previous
//
#include <hip/hip_runtime.h>
#include <math.h>

// MSAPairWeightedAveraging — round 21: k2+k3 fused into k23 (block per i, 8 waves:
// 3x k2-chunk per wave -> logits in padded LDS -> in-block softmax, wave w = head w).
// Stats via __shfl (no LDS/barrier in the chunk phase). Bytes identical to k2->k3.
// S=256, N=384, C_M=64, C_Z=128, C=32, H=8, H*C=256.
// ws: mterm f32[384] | wbl bf16[8,384,384] | vT bf16[8,8192,384] | g bf16[98304,256]
//     | ob bf16[98304,256] | BTg bf16[512,64] | w2bf bf16[16,128] | consts f32[32]

#define SS 256
#define NN 384
#define CM 64
#define CZ 128
#define HH 8
#define HC 256
#define NV 25165824   // S*N*HC

typedef __attribute__((ext_vector_type(8))) short short8v;
typedef __attribute__((ext_vector_type(8))) unsigned short ushort8v;
typedef __attribute__((ext_vector_type(4))) unsigned short ushort4v;
typedef __attribute__((ext_vector_type(4))) float f32x4;

static __device__ __forceinline__ float bf2f(unsigned short u) {
    union { unsigned int i; float f; } x; x.i = ((unsigned int)u) << 16; return x.f;
}
static __device__ __forceinline__ unsigned short f2bf(float f) {
    union { float f; unsigned int i; } x; x.f = f;
    unsigned int r = x.i + 0x7FFFu + ((x.i >> 16) & 1u);   // RNE
    return (unsigned short)(r >> 16);
}
static __device__ __forceinline__ void gload_lds16(const void* g, void* l) {
    __builtin_amdgcn_global_load_lds((const __attribute__((address_space(1))) void*)g,
                                     (__attribute__((address_space(3))) void*)l, 16, 0, 0);
}

// ---------------- k_prep: fused {mask decode | LN-fold w_b | transpose w_v/w_g} ----------------
__global__ __launch_bounds__(256) void k_prep(
    const unsigned int* __restrict__ mu, const float* __restrict__ lnzw,
    const float* __restrict__ lnzb, const float* __restrict__ w_b,
    const float* __restrict__ w_v, const float* __restrict__ w_g,
    float* __restrict__ mterm, unsigned short* __restrict__ w2bf,
    float* __restrict__ consts, unsigned short* __restrict__ BTg)
{
    const int b = blockIdx.x, tid = threadIdx.x;
    if (b == 0) {
        __shared__ int byteLayout;
        if (tid == 0) byteLayout = 0;
        __syncthreads();
        if (tid < 96) {
            unsigned int u = mu[tid];
            if (u != 0u && u != 1u && u != 0x3F800000u) atomicOr(&byteLayout, 1);
        }
        __syncthreads();
        for (int j = tid; j < 384; j += 256) {
            int val;
            if (byteLayout) val = ((const unsigned char*)mu)[j];
            else            val = (mu[j] != 0u);
            mterm[j] = val ? 0.0f : -1e9f;
        }
    } else if (b == 1) {
        __shared__ float pA[128][8], pB[128][8];
        const int c = tid & 127;
        if (tid < 128) {
            float lw = lnzw[c], lb = lnzb[c];
            float4 wb0 = *(const float4*)&w_b[c * 8];
            float4 wb1 = *(const float4*)&w_b[c * 8 + 4];
            float wv[8] = {wb0.x, wb0.y, wb0.z, wb0.w, wb1.x, wb1.y, wb1.z, wb1.w};
            #pragma unroll
            for (int h = 0; h < 8; h++) {
                w2bf[h * CZ + c]       = f2bf(lw * wv[h]);
                w2bf[(8 + h) * CZ + c] = 0;
                pA[c][h] = lw * wv[h];
                pB[c][h] = lb * wv[h];
            }
        }
        __syncthreads();
        if (tid < 8) {
            float A = 0.f, B = 0.f;
            for (int q = 0; q < 128; q++) { A += pA[q][tid]; B += pB[q][tid]; }
            consts[tid] = A; consts[16 + tid] = B;
            consts[8 + tid] = 0.f; consts[24 + tid] = 0.f;
        }
    } else {
        const int col = (b - 2) * 4 + (tid >> 6);
        const int k   = tid & 63;
        float w = (col < 256) ? w_v[k * 256 + col] : w_g[k * 256 + (col - 256)];
        BTg[col * 64 + (k ^ ((col & 7) << 3))] = f2bf(w);
    }
}

// ---------------- k1b: fused LN + 8-wave one-family-per-wave barrier-light GEMM ----------------
__global__ __launch_bounds__(512) void k1b_vg(
    const unsigned short* __restrict__ BTg, const float* __restrict__ m,
    const float* __restrict__ lnw, const float* __restrict__ lnb,
    unsigned short* __restrict__ vT, unsigned short* __restrict__ gout)
{
    __shared__ unsigned short Wl[32768];  // [512 cols][64 k] swizzled; wave-partitioned (8KB/wave)
    __shared__ unsigned short Al[4096];   // [64 rows][64 k] swizzled; cooperative LN output
    const int tid = threadIdx.x, wid = tid >> 6, lane = tid & 63;
    const int rl = lane & 15, kc = lane >> 4;
    const int fam = wid >> 2, wq = wid & 3;
    const int rowBase = blockIdx.x * 64;       // 64 | 384 -> never straddles s
    const int s = rowBase / NN, j0 = rowBase - s * NN;

    // 1) oldest in vmcnt queue: LN params, then this wave's 8 m-rows
    const float lw = lnw[lane], lb = lnb[lane];
    float mx[8];
    #pragma unroll
    for (int rr = 0; rr < 8; rr++)
        mx[rr] = m[(size_t)(rowBase + wid * 8 + rr) * CM + lane];
    __builtin_amdgcn_sched_barrier(0);

    // 2) newest: wave-private W staging (stays in flight under LN)
    #pragma unroll
    for (int it = 0; it < 8; it++) {
        int eoff = wid * 4096 + it * 512;          // == (fam*16384 + wq*4096) + it*512
        gload_lds16(BTg + eoff + lane * 8, (void*)((char*)Wl + eoff * 2));
    }
    __builtin_amdgcn_sched_barrier(0);

    // 3) LN of this wave's 8 rows -> Al (consumes mx at vmcnt(8))
    #pragma unroll
    for (int rr = 0; rr < 8; rr++) {
        int row = wid * 8 + rr;
        float x = mx[rr];
        float s1 = x, s2 = x * x;
        #pragma unroll
        for (int off = 32; off; off >>= 1) {
            s1 += __shfl_xor(s1, off);
            s2 += __shfl_xor(s2, off);
        }
        float mu  = s1 * (1.0f / CM);
        float var = s2 * (1.0f / CM) - mu * mu;
        float y = (x - mu) * rsqrtf(var + 1e-5f) * lw + lb;
        Al[row * 64 + (lane ^ ((row & 7) << 3))] = f2bf(y);
    }

    // 4) Al visibility: own ds_writes drained, then block barrier (vmcnt NOT drained)
    asm volatile("s_waitcnt lgkmcnt(0)" ::: "memory");
    __builtin_amdgcn_s_barrier();
    __builtin_amdgcn_sched_barrier(0);
    // 5) this wave's W staging complete
    asm volatile("s_waitcnt vmcnt(0)" ::: "memory");
    __builtin_amdgcn_sched_barrier(0);

    // A fragments
    short8v al[2][4];
    #pragma unroll
    for (int ks = 0; ks < 2; ks++)
        #pragma unroll
        for (int q = 0; q < 4; q++) {
            int row = q * 16 + rl;
            al[ks][q] = *(const short8v*)&Al[(row * 64 + ks * 32 + kc * 8) ^ ((row & 7) << 3)];
        }

    unsigned short* WP = Wl + wid * 4096;   // this wave's 8KB W region (cols local 0..63)
    unsigned short* VS = WP;                // reused as wave-private scratch after wf reads

    f32x4 acc[4][4] = {};
    if (fam == 0) {
        // v: A=al so j lands in reg dim
        #pragma unroll
        for (int ks = 0; ks < 2; ks++) {
            short8v wf[4];
            #pragma unroll
            for (int q = 0; q < 4; q++) {
                int cl = q * 16 + rl;   // local col; global col = wq*64+cl, (col&7)==(cl&7)
                wf[q] = *(const short8v*)&WP[(cl * 64 + ks * 32 + kc * 8) ^ ((cl & 7) << 3)];
            }
            #pragma unroll
            for (int mi = 0; mi < 4; mi++)
                #pragma unroll
                for (int nf = 0; nf < 4; nf++)
                    acc[mi][nf] = __builtin_amdgcn_mfma_f32_16x16x32_bf16(al[ks][mi], wf[nf], acc[mi][nf], 0, 0, 0);
        }
        #pragma unroll
        for (int mi = 0; mi < 4; mi++) {
            const int jb = mi * 16 + kc * 4;
            #pragma unroll
            for (int nf = 0; nf < 4; nf++) {
                int hcl = nf * 16 + rl;
                ushort4v o4;
                #pragma unroll
                for (int r = 0; r < 4; r++) o4[r] = f2bf(acc[mi][nf][r]);
                *(ushort4v*)&VS[(hcl * 64 + jb) ^ ((hcl & 7) << 3)] = o4;
            }
        }
        #pragma unroll
        for (int p = 0; p < 8; p++) {
            int hcl = p * 8 + (lane >> 3);
            int j8  = (lane & 7) * 8;
            ushort8v val = *(const ushort8v*)&VS[(hcl * 64 + j8) ^ ((hcl & 7) << 3)];
            int hc = wq * 64 + hcl;
            size_t vrow = (size_t)((hc >> 5) * 8192 + s * 32 + (hc & 31));
            *(ushort8v*)&vT[vrow * NN + j0 + j8] = val;
        }
    } else {
        // g: A=wf so hc lands in reg dim
        #pragma unroll
        for (int ks = 0; ks < 2; ks++) {
            short8v wf[4];
            #pragma unroll
            for (int q = 0; q < 4; q++) {
                int cl = q * 16 + rl;
                wf[q] = *(const short8v*)&WP[(cl * 64 + ks * 32 + kc * 8) ^ ((cl & 7) << 3)];
            }
            #pragma unroll
            for (int mi = 0; mi < 4; mi++)
                #pragma unroll
                for (int nf = 0; nf < 4; nf++)
                    acc[mi][nf] = __builtin_amdgcn_mfma_f32_16x16x32_bf16(wf[mi], al[ks][nf], acc[mi][nf], 0, 0, 0);
        }
        #pragma unroll
        for (int mi = 0; mi < 4; mi++) {
            const int hcb = mi * 16 + kc * 4;   // local hc 0..63
            #pragma unroll
            for (int nf = 0; nf < 4; nf++) {
                int rowl = nf * 16 + rl;
                ushort4v o4;
                #pragma unroll
                for (int r = 0; r < 4; r++)
                    o4[r] = f2bf(1.0f / (1.0f + __expf(-acc[mi][nf][r])));
                *(ushort4v*)&VS[(rowl * 64 + hcb) ^ ((rowl & 7) << 3)] = o4;
            }
        }
        #pragma unroll
        for (int p = 0; p < 8; p++) {
            int rowl = p * 8 + (lane >> 3);
            int hc8  = (lane & 7) * 8;
            ushort8v val = *(const ushort8v*)&VS[(rowl * 64 + hc8) ^ ((rowl & 7) << 3)];
            *(ushort8v*)&gout[(size_t)(rowBase + rowl) * HC + wq * 64 + hc8] = val;
        }
    }
}

// ---------------- k23: fused LN(z)@W2 projection + mask + softmax, block per i ----------------
// 8 waves; wave handles rows j = wid*48 + ch*16 + rl over 3 chunks (k2's exact chunk math,
// stats via __shfl); logits -> Llog[384][10] bf16 (pad 10 -> conflict-free softmax reads);
// barrier; wave w softmaxes h=w over all 384 j (k3's exact ops/stores).
__global__ __launch_bounds__(512) void k23_lnz_softmax(
    const float* __restrict__ z, const unsigned short* __restrict__ w2bf,
    const float* __restrict__ consts, const float* __restrict__ mterm,
    unsigned short* __restrict__ wbl)
{
    __shared__ unsigned short Llog[384 * 10];   // [j][h] padded, 7.5 KB
    const int tid = threadIdx.x, wid = tid >> 6, lane = tid & 63;
    const int rl = lane & 15, kc = lane >> 4;
    const int i = blockIdx.x;

    // hoisted B fragments (identical bytes each chunk)
    short8v bf[4];
    #pragma unroll
    for (int ks = 0; ks < 4; ks++)
        bf[ks] = *(const short8v*)&w2bf[rl * CZ + ks * 32 + kc * 8];
    const float Ah = consts[rl], Bh = consts[16 + rl];

    #pragma unroll
    for (int ch = 0; ch < 3; ch++) {
        const int jb = wid * 48 + ch * 16;
        const float* zr = z + ((size_t)i * NN + jb + rl) * CZ + kc * 8;

        float s1 = 0.f, s2 = 0.f;
        short8v af[4];
        #pragma unroll
        for (int ks = 0; ks < 4; ks++) {
            float4 z0 = *(const float4*)(zr + ks * 32);
            float4 z1 = *(const float4*)(zr + ks * 32 + 4);
            float zz[8] = {z0.x, z0.y, z0.z, z0.w, z1.x, z1.y, z1.z, z1.w};
            short8v a;
            #pragma unroll
            for (int q = 0; q < 8; q++) {
                s1 += zz[q];
                s2 += zz[q] * zz[q];
                a[q] = (short)f2bf(zz[q]);
            }
            af[ks] = a;
        }
        s1 += __shfl_xor(s1, 16); s2 += __shfl_xor(s2, 16);
        s1 += __shfl_xor(s1, 32); s2 += __shfl_xor(s2, 32);
        // lane l now holds full stats of row (l&15)

        f32x4 acc = {};
        #pragma unroll
        for (int ks = 0; ks < 4; ks++)
            acc = __builtin_amdgcn_mfma_f32_16x16x32_bf16(af[ks], bf[ks], acc, 0, 0, 0);

        unsigned short pv[4];
        #pragma unroll
        for (int reg = 0; reg < 4; reg++) {
            int r = 4 * kc + reg;
            float S1 = __shfl(s1, r);
            float S2 = __shfl(s2, r);
            float mu   = S1 * (1.0f / CZ);
            float var  = S2 * (1.0f / CZ) - mu * mu;
            float rstd = rsqrtf(var + 1e-5f);
            float b = rstd * acc[reg] - rstd * mu * Ah + Bh + mterm[jb + r];
            pv[reg] = f2bf(b);
        }
        if (rl < 8) {
            #pragma unroll
            for (int reg = 0; reg < 4; reg++)
                Llog[(jb + 4 * kc + reg) * 10 + rl] = pv[reg];
        }
    }
    __syncthreads();

    // softmax: wave wid = head wid, over j = lane + e*64
    unsigned short* p = wbl + ((size_t)wid * NN + i) * NN;
    float x[6];
    float mx = -1e30f;
    #pragma unroll
    for (int e = 0; e < 6; e++) { x[e] = bf2f(Llog[(lane + e * 64) * 10 + wid]); mx = fmaxf(mx, x[e]); }
    #pragma unroll
    for (int off = 32; off; off >>= 1) mx = fmaxf(mx, __shfl_xor(mx, off));
    float sum = 0.f;
    #pragma unroll
    for (int e = 0; e < 6; e++) { x[e] = expf(x[e] - mx); sum += x[e]; }
    #pragma unroll
    for (int off = 32; off; off >>= 1) sum += __shfl_xor(sum, off);
    float inv = 1.0f / sum;
    #pragma unroll
    for (int e = 0; e < 6; e++) p[lane + e * 64] = f2bf(x[e] * inv);
}

// ---------------- k4: per-h MFMA GEMM; operand-swapped -> packed 8B ob stores ----------------
__global__ __launch_bounds__(256) void k4_mfma(
    const unsigned short* __restrict__ wbf, const unsigned short* __restrict__ vT,
    unsigned short* __restrict__ ob)
{
    __shared__ unsigned short Al[128 * 32];
    __shared__ unsigned short Bl[128 * 32];
    const int tid  = threadIdx.x;
    const int wid  = tid >> 6, lane = tid & 63;
    const int wm   = wid >> 1, wn = wid & 1;
    const int h    = blockIdx.z;
    const int i0   = blockIdx.y * 128;
    const int n0   = blockIdx.x * 128;
    const unsigned short* Ag = wbf + (size_t)h * NN * NN;
    const unsigned short* Bg = vT  + (size_t)h * 8192 * NN;

    f32x4 acc[4][4] = {};

    const int lrow = lane >> 2, lchunk = lane & 3;
    for (int k0 = 0; k0 < NN; k0 += 32) {
        #pragma unroll
        for (int q = 0; q < 2; q++) {
            int issue = wid * 2 + q;
            int r = issue * 16 + lrow;
            gload_lds16(Ag + (size_t)(i0 + r) * NN + k0 + lchunk * 8,
                        (void*)((char*)Al + issue * 1024));
            gload_lds16(Bg + (size_t)(n0 + r) * NN + k0 + lchunk * 8,
                        (void*)((char*)Bl + issue * 1024));
        }
        __syncthreads();

        short8v a[4], b[4];
        #pragma unroll
        for (int mi = 0; mi < 4; mi++)
            a[mi] = *(const short8v*)&Al[(wm * 64 + mi * 16 + (lane & 15)) * 32 + (lane >> 4) * 8];
        #pragma unroll
        for (int ni = 0; ni < 4; ni++)
            b[ni] = *(const short8v*)&Bl[(wn * 64 + ni * 16 + (lane & 15)) * 32 + (lane >> 4) * 8];
        #pragma unroll
        for (int mi = 0; mi < 4; mi++)
            #pragma unroll
            for (int ni = 0; ni < 4; ni++)
                acc[mi][ni] = __builtin_amdgcn_mfma_f32_16x16x32_bf16(b[ni], a[mi], acc[mi][ni], 0, 0, 0);
        __syncthreads();
    }

    #pragma unroll
    for (int mi = 0; mi < 4; mi++) {
        const int i = i0 + wm * 64 + mi * 16 + (lane & 15);
        #pragma unroll
        for (int ni = 0; ni < 4; ni++) {
            const int sc0 = n0 + wn * 64 + ni * 16 + ((lane >> 4) << 2);
            const int s = sc0 >> 5, c0 = sc0 & 31;
            ushort4v o4;
            #pragma unroll
            for (int r = 0; r < 4; r++) o4[r] = f2bf(acc[mi][ni][r]);
            *(ushort4v*)&ob[((size_t)s * NN + i) * HC + (h << 5) + c0] = o4;
        }
    }
}

// ---------------- k5: out[98304,64] = (o .* g)[98304,256] @ w_out[256,64]  via MFMA ----------------
__global__ __launch_bounds__(256) void k5_mfma(
    const unsigned short* __restrict__ ob, const unsigned short* __restrict__ g,
    const float* __restrict__ w_out, float* __restrict__ out)
{
    __shared__ unsigned short WT[64 * 256];   // w_out^T bf16, swizzled: idx ^ ((c&7)<<3)
    const int tid = threadIdx.x, wid = tid >> 6, lane = tid & 63;
    #pragma unroll
    for (int e = 0; e < 16; e++) {
        int fidx = (tid + e * 256) * 4;
        float4 w4 = *(const float4*)&w_out[fidx];
        int k = fidx >> 6, c0 = fidx & 63;
        float wv[4] = {w4.x, w4.y, w4.z, w4.w};
        #pragma unroll
        for (int q = 0; q < 4; q++) {
            int c = c0 + q;
            WT[(((c << 8) + k)) ^ ((c & 7) << 3)] = f2bf(wv[q]);
        }
    }
    __syncthreads();

    const size_t rowbase = (size_t)blockIdx.x * 64 + wid * 16;
    const int arow = lane & 15, achunk = lane >> 4;
    const unsigned short* op = ob + (rowbase + arow) * HC + achunk * 8;
    const unsigned short* gp = g  + (rowbase + arow) * HC + achunk * 8;

    f32x4 acc[4] = {};
    #pragma unroll
    for (int ks = 0; ks < 8; ks++) {
        ushort8v o8 = *(const ushort8v*)(op + ks * 32);
        ushort8v g8 = *(const ushort8v*)(gp + ks * 32);
        short8v a;
        #pragma unroll
        for (int q = 0; q < 8; q++)
            a[q] = (short)f2bf(bf2f(o8[q]) * bf2f(g8[q]));
        #pragma unroll
        for (int nf = 0; nf < 4; nf++) {
            const int c = nf * 16 + arow;
            short8v b = *(const short8v*)&WT[(((c << 8) + ks * 32 + achunk * 8)) ^ ((c & 7) << 3)];
            acc[nf] = __builtin_amdgcn_mfma_f32_16x16x32_bf16(a, b, acc[nf], 0, 0, 0);
        }
    }
    #pragma unroll
    for (int nf = 0; nf < 4; nf++)
        #pragma unroll
        for (int r = 0; r < 4; r++)
            out[(rowbase + achunk * 4 + r) * CM + nf * 16 + arow] = acc[nf][r];
}

extern "C" void kernel_launch(void* const* d_in, const int* in_sizes, int n_in,
                              void* d_out, int out_size, void* d_ws, size_t ws_size,
                              hipStream_t stream)
{
    const float* m      = (const float*)d_in[0];
    const float* z      = (const float*)d_in[1];
    const unsigned int* mask_raw = (const unsigned int*)d_in[2];
    const float* ln_m_w = (const float*)d_in[3];
    const float* ln_m_b = (const float*)d_in[4];
    const float* ln_z_w = (const float*)d_in[5];
    const float* ln_z_b = (const float*)d_in[6];
    const float* w_v    = (const float*)d_in[7];
    const float* w_b    = (const float*)d_in[8];
    const float* w_g    = (const float*)d_in[9];
    const float* w_out  = (const float*)d_in[10];
    float* out = (float*)d_out;

    // ws layout
    float* mterm = (float*)d_ws;
    unsigned short* wbl = (unsigned short*)(mterm + 384);
    unsigned short* vT  = wbl + 1179648;
    unsigned short* g   = vT + NV;
    unsigned short* ob  = g + NV;
    unsigned short* BTg = ob + NV;             // [512][64]
    unsigned short* w2bf = BTg + 32768;        // [16][128]
    float* consts = (float*)(w2bf + 2048);     // [32]

    k_prep<<<130, 256, 0, stream>>>(mask_raw, ln_z_w, ln_z_b, w_b, w_v, w_g,
                                    mterm, w2bf, consts, BTg);
    k1b_vg<<<1536, 512, 0, stream>>>(BTg, m, ln_m_w, ln_m_b, vT, g);
    k23_lnz_softmax<<<384, 512, 0, stream>>>(z, w2bf, consts, mterm, wbl);
    k4_mfma<<<dim3(64, 3, 8), 256, 0, stream>>>(wbl, vT, ob);
    k5_mfma<<<1536, 256, 0, stream>>>(ob, g, w_out, out);
}

// Round 24
// 123.861 us; speedup vs baseline: 1.0859x; 1.0002x over previous
//
#include <hip/hip_runtime.h>
#include <math.h>

// MSAPairWeightedAveraging — round 23: k1b and k23 merged into ONE heterogeneous
// dispatch (blocks 0..383 = k23 LN(z)+softmax; blocks 384..1919 = k1b LN(m)+v/g GEMM).
// No data dependency between the halves; k23 hides inside k1b's latency stalls.
// S=256, N=384, C_M=64, C_Z=128, C=32, H=8, H*C=256.
// ws: mterm f32[384] | wbl bf16[8,384,384] | vT bf16[8,8192,384] | g bf16[98304,256]
//     | ob bf16[98304,256] | BTg bf16[512,64] | w2bf bf16[16,128] | consts f32[32]

#define SS 256
#define NN 384
#define CM 64
#define CZ 128
#define HH 8
#define HC 256
#define NV 25165824   // S*N*HC

typedef __attribute__((ext_vector_type(8))) short short8v;
typedef __attribute__((ext_vector_type(8))) unsigned short ushort8v;
typedef __attribute__((ext_vector_type(4))) unsigned short ushort4v;
typedef __attribute__((ext_vector_type(4))) float f32x4;

static __device__ __forceinline__ float bf2f(unsigned short u) {
    union { unsigned int i; float f; } x; x.i = ((unsigned int)u) << 16; return x.f;
}
static __device__ __forceinline__ unsigned short f2bf(float f) {
    union { float f; unsigned int i; } x; x.f = f;
    unsigned int r = x.i + 0x7FFFu + ((x.i >> 16) & 1u);   // RNE
    return (unsigned short)(r >> 16);
}
static __device__ __forceinline__ void gload_lds16(const void* g, void* l) {
    __builtin_amdgcn_global_load_lds((const __attribute__((address_space(1))) void*)g,
                                     (__attribute__((address_space(3))) void*)l, 16, 0, 0);
}

// ---------------- k_prep: fused {mask decode | LN-fold w_b | transpose w_v/w_g} ----------------
__global__ __launch_bounds__(256) void k_prep(
    const unsigned int* __restrict__ mu, const float* __restrict__ lnzw,
    const float* __restrict__ lnzb, const float* __restrict__ w_b,
    const float* __restrict__ w_v, const float* __restrict__ w_g,
    float* __restrict__ mterm, unsigned short* __restrict__ w2bf,
    float* __restrict__ consts, unsigned short* __restrict__ BTg)
{
    const int b = blockIdx.x, tid = threadIdx.x;
    if (b == 0) {
        __shared__ int byteLayout;
        if (tid == 0) byteLayout = 0;
        __syncthreads();
        if (tid < 96) {
            unsigned int u = mu[tid];
            if (u != 0u && u != 1u && u != 0x3F800000u) atomicOr(&byteLayout, 1);
        }
        __syncthreads();
        for (int j = tid; j < 384; j += 256) {
            int val;
            if (byteLayout) val = ((const unsigned char*)mu)[j];
            else            val = (mu[j] != 0u);
            mterm[j] = val ? 0.0f : -1e9f;
        }
    } else if (b == 1) {
        __shared__ float pA[128][8], pB[128][8];
        const int c = tid & 127;
        if (tid < 128) {
            float lw = lnzw[c], lb = lnzb[c];
            float4 wb0 = *(const float4*)&w_b[c * 8];
            float4 wb1 = *(const float4*)&w_b[c * 8 + 4];
            float wv[8] = {wb0.x, wb0.y, wb0.z, wb0.w, wb1.x, wb1.y, wb1.z, wb1.w};
            #pragma unroll
            for (int h = 0; h < 8; h++) {
                w2bf[h * CZ + c]       = f2bf(lw * wv[h]);
                w2bf[(8 + h) * CZ + c] = 0;
                pA[c][h] = lw * wv[h];
                pB[c][h] = lb * wv[h];
            }
        }
        __syncthreads();
        if (tid < 8) {
            float A = 0.f, B = 0.f;
            for (int q = 0; q < 128; q++) { A += pA[q][tid]; B += pB[q][tid]; }
            consts[tid] = A; consts[16 + tid] = B;
            consts[8 + tid] = 0.f; consts[24 + tid] = 0.f;
        }
    } else {
        const int col = (b - 2) * 4 + (tid >> 6);
        const int k   = tid & 63;
        float w = (col < 256) ? w_v[k * 256 + col] : w_g[k * 256 + (col - 256)];
        BTg[col * 64 + (k ^ ((col & 7) << 3))] = f2bf(w);
    }
}

// ---------------- k1b23: heterogeneous fused dispatch ----------------
// blocks 0..383:    k23 body (LN(z)@W2 + mask + softmax) for pair-row i = blockIdx.x
// blocks 384..1919: k1b body (fused LN(m) + 8-wave v/g GEMM), rowBase = (blockIdx.x-384)*64
__global__ __launch_bounds__(512) void k1b23(
    const unsigned short* __restrict__ BTg, const float* __restrict__ m,
    const float* __restrict__ lnw, const float* __restrict__ lnb,
    unsigned short* __restrict__ vT, unsigned short* __restrict__ gout,
    const float* __restrict__ z, const unsigned short* __restrict__ w2bf,
    const float* __restrict__ consts, const float* __restrict__ mterm,
    unsigned short* __restrict__ wbl)
{
    __shared__ unsigned short SMEM[36864];   // 72 KB union
    const int tid = threadIdx.x, wid = tid >> 6, lane = tid & 63;
    const int rl = lane & 15, kc = lane >> 4;

    if (blockIdx.x < 384) {
        // ================= k23 branch =================
        unsigned short* Llog = SMEM;          // [384][10] bf16, 7.5 KB
        const int i = blockIdx.x;

        short8v bf[4];
        #pragma unroll
        for (int ks = 0; ks < 4; ks++)
            bf[ks] = *(const short8v*)&w2bf[rl * CZ + ks * 32 + kc * 8];
        const float Ah = consts[rl], Bh = consts[16 + rl];

        #pragma unroll
        for (int ch = 0; ch < 3; ch++) {
            const int jb = wid * 48 + ch * 16;
            const float* zr = z + ((size_t)i * NN + jb + rl) * CZ + kc * 8;

            float s1 = 0.f, s2 = 0.f;
            short8v af[4];
            #pragma unroll
            for (int ks = 0; ks < 4; ks++) {
                float4 z0 = *(const float4*)(zr + ks * 32);
                float4 z1 = *(const float4*)(zr + ks * 32 + 4);
                float zz[8] = {z0.x, z0.y, z0.z, z0.w, z1.x, z1.y, z1.z, z1.w};
                short8v a;
                #pragma unroll
                for (int q = 0; q < 8; q++) {
                    s1 += zz[q];
                    s2 += zz[q] * zz[q];
                    a[q] = (short)f2bf(zz[q]);
                }
                af[ks] = a;
            }
            s1 += __shfl_xor(s1, 16); s2 += __shfl_xor(s2, 16);
            s1 += __shfl_xor(s1, 32); s2 += __shfl_xor(s2, 32);

            f32x4 acc = {};
            #pragma unroll
            for (int ks = 0; ks < 4; ks++)
                acc = __builtin_amdgcn_mfma_f32_16x16x32_bf16(af[ks], bf[ks], acc, 0, 0, 0);

            unsigned short pv[4];
            #pragma unroll
            for (int reg = 0; reg < 4; reg++) {
                int r = 4 * kc + reg;
                float S1 = __shfl(s1, r);
                float S2 = __shfl(s2, r);
                float mu   = S1 * (1.0f / CZ);
                float var  = S2 * (1.0f / CZ) - mu * mu;
                float rstd = rsqrtf(var + 1e-5f);
                float b = rstd * acc[reg] - rstd * mu * Ah + Bh + mterm[jb + r];
                pv[reg] = f2bf(b);
            }
            if (rl < 8) {
                #pragma unroll
                for (int reg = 0; reg < 4; reg++)
                    Llog[(jb + 4 * kc + reg) * 10 + rl] = pv[reg];
            }
        }
        __syncthreads();

        unsigned short* p = wbl + ((size_t)wid * NN + i) * NN;
        float x[6];
        float mx = -1e30f;
        #pragma unroll
        for (int e = 0; e < 6; e++) { x[e] = bf2f(Llog[(lane + e * 64) * 10 + wid]); mx = fmaxf(mx, x[e]); }
        #pragma unroll
        for (int off = 32; off; off >>= 1) mx = fmaxf(mx, __shfl_xor(mx, off));
        float sum = 0.f;
        #pragma unroll
        for (int e = 0; e < 6; e++) { x[e] = expf(x[e] - mx); sum += x[e]; }
        #pragma unroll
        for (int off = 32; off; off >>= 1) sum += __shfl_xor(sum, off);
        float inv = 1.0f / sum;
        #pragma unroll
        for (int e = 0; e < 6; e++) p[lane + e * 64] = f2bf(x[e] * inv);
        return;
    }

    // ================= k1b branch =================
    unsigned short* Wl = SMEM;            // [512 cols][64 k] swizzled; wave-partitioned
    unsigned short* Al = SMEM + 32768;    // [64 rows][64 k] swizzled; cooperative LN output
    const int fam = wid >> 2, wq = wid & 3;
    const int rowBase = (blockIdx.x - 384) * 64;   // 64 | 384 -> never straddles s
    const int s = rowBase / NN, j0 = rowBase - s * NN;

    // 1) oldest in vmcnt queue: LN params, then this wave's 8 m-rows
    const float lw = lnw[lane], lb = lnb[lane];
    float mx8[8];
    #pragma unroll
    for (int rr = 0; rr < 8; rr++)
        mx8[rr] = m[(size_t)(rowBase + wid * 8 + rr) * CM + lane];
    __builtin_amdgcn_sched_barrier(0);

    // 2) newest: wave-private W staging (stays in flight under LN)
    #pragma unroll
    for (int it = 0; it < 8; it++) {
        int eoff = wid * 4096 + it * 512;
        gload_lds16(BTg + eoff + lane * 8, (void*)((char*)Wl + eoff * 2));
    }
    __builtin_amdgcn_sched_barrier(0);

    // 3) LN of this wave's 8 rows -> Al
    #pragma unroll
    for (int rr = 0; rr < 8; rr++) {
        int row = wid * 8 + rr;
        float x = mx8[rr];
        float s1 = x, s2 = x * x;
        #pragma unroll
        for (int off = 32; off; off >>= 1) {
            s1 += __shfl_xor(s1, off);
            s2 += __shfl_xor(s2, off);
        }
        float mu  = s1 * (1.0f / CM);
        float var = s2 * (1.0f / CM) - mu * mu;
        float y = (x - mu) * rsqrtf(var + 1e-5f) * lw + lb;
        Al[row * 64 + (lane ^ ((row & 7) << 3))] = f2bf(y);
    }

    // 4) Al visibility: own ds_writes drained, then block barrier (vmcnt NOT drained)
    asm volatile("s_waitcnt lgkmcnt(0)" ::: "memory");
    __builtin_amdgcn_s_barrier();
    __builtin_amdgcn_sched_barrier(0);
    // 5) this wave's W staging complete
    asm volatile("s_waitcnt vmcnt(0)" ::: "memory");
    __builtin_amdgcn_sched_barrier(0);

    // A fragments
    short8v al[2][4];
    #pragma unroll
    for (int ks = 0; ks < 2; ks++)
        #pragma unroll
        for (int q = 0; q < 4; q++) {
            int row = q * 16 + rl;
            al[ks][q] = *(const short8v*)&Al[(row * 64 + ks * 32 + kc * 8) ^ ((row & 7) << 3)];
        }

    unsigned short* WP = Wl + wid * 4096;
    unsigned short* VS = WP;

    f32x4 acc[4][4] = {};
    if (fam == 0) {
        // v: A=al so j lands in reg dim
        #pragma unroll
        for (int ks = 0; ks < 2; ks++) {
            short8v wf[4];
            #pragma unroll
            for (int q = 0; q < 4; q++) {
                int cl = q * 16 + rl;
                wf[q] = *(const short8v*)&WP[(cl * 64 + ks * 32 + kc * 8) ^ ((cl & 7) << 3)];
            }
            #pragma unroll
            for (int mi = 0; mi < 4; mi++)
                #pragma unroll
                for (int nf = 0; nf < 4; nf++)
                    acc[mi][nf] = __builtin_amdgcn_mfma_f32_16x16x32_bf16(al[ks][mi], wf[nf], acc[mi][nf], 0, 0, 0);
        }
        #pragma unroll
        for (int mi = 0; mi < 4; mi++) {
            const int jb = mi * 16 + kc * 4;
            #pragma unroll
            for (int nf = 0; nf < 4; nf++) {
                int hcl = nf * 16 + rl;
                ushort4v o4;
                #pragma unroll
                for (int r = 0; r < 4; r++) o4[r] = f2bf(acc[mi][nf][r]);
                *(ushort4v*)&VS[(hcl * 64 + jb) ^ ((hcl & 7) << 3)] = o4;
            }
        }
        #pragma unroll
        for (int p = 0; p < 8; p++) {
            int hcl = p * 8 + (lane >> 3);
            int j8  = (lane & 7) * 8;
            ushort8v val = *(const ushort8v*)&VS[(hcl * 64 + j8) ^ ((hcl & 7) << 3)];
            int hc = wq * 64 + hcl;
            size_t vrow = (size_t)((hc >> 5) * 8192 + s * 32 + (hc & 31));
            *(ushort8v*)&vT[vrow * NN + j0 + j8] = val;
        }
    } else {
        // g: A=wf so hc lands in reg dim
        #pragma unroll
        for (int ks = 0; ks < 2; ks++) {
            short8v wf[4];
            #pragma unroll
            for (int q = 0; q < 4; q++) {
                int cl = q * 16 + rl;
                wf[q] = *(const short8v*)&WP[(cl * 64 + ks * 32 + kc * 8) ^ ((cl & 7) << 3)];
            }
            #pragma unroll
            for (int mi = 0; mi < 4; mi++)
                #pragma unroll
                for (int nf = 0; nf < 4; nf++)
                    acc[mi][nf] = __builtin_amdgcn_mfma_f32_16x16x32_bf16(wf[mi], al[ks][nf], acc[mi][nf], 0, 0, 0);
        }
        #pragma unroll
        for (int mi = 0; mi < 4; mi++) {
            const int hcb = mi * 16 + kc * 4;
            #pragma unroll
            for (int nf = 0; nf < 4; nf++) {
                int rowl = nf * 16 + rl;
                ushort4v o4;
                #pragma unroll
                for (int r = 0; r < 4; r++)
                    o4[r] = f2bf(1.0f / (1.0f + __expf(-acc[mi][nf][r])));
                *(ushort4v*)&VS[(rowl * 64 + hcb) ^ ((rowl & 7) << 3)] = o4;
            }
        }
        #pragma unroll
        for (int p = 0; p < 8; p++) {
            int rowl = p * 8 + (lane >> 3);
            int hc8  = (lane & 7) * 8;
            ushort8v val = *(const ushort8v*)&VS[(rowl * 64 + hc8) ^ ((rowl & 7) << 3)];
            *(ushort8v*)&gout[(size_t)(rowBase + rowl) * HC + wq * 64 + hc8] = val;
        }
    }
}

// ---------------- k4: per-h MFMA GEMM; operand-swapped -> packed 8B ob stores ----------------
__global__ __launch_bounds__(256) void k4_mfma(
    const unsigned short* __restrict__ wbf, const unsigned short* __restrict__ vT,
    unsigned short* __restrict__ ob)
{
    __shared__ unsigned short Al[128 * 32];
    __shared__ unsigned short Bl[128 * 32];
    const int tid  = threadIdx.x;
    const int wid  = tid >> 6, lane = tid & 63;
    const int wm   = wid >> 1, wn = wid & 1;
    const int h    = blockIdx.z;
    const int i0   = blockIdx.y * 128;
    const int n0   = blockIdx.x * 128;
    const unsigned short* Ag = wbf + (size_t)h * NN * NN;
    const unsigned short* Bg = vT  + (size_t)h * 8192 * NN;

    f32x4 acc[4][4] = {};

    const int lrow = lane >> 2, lchunk = lane & 3;
    for (int k0 = 0; k0 < NN; k0 += 32) {
        #pragma unroll
        for (int q = 0; q < 2; q++) {
            int issue = wid * 2 + q;
            int r = issue * 16 + lrow;
            gload_lds16(Ag + (size_t)(i0 + r) * NN + k0 + lchunk * 8,
                        (void*)((char*)Al + issue * 1024));
            gload_lds16(Bg + (size_t)(n0 + r) * NN + k0 + lchunk * 8,
                        (void*)((char*)Bl + issue * 1024));
        }
        __syncthreads();

        short8v a[4], b[4];
        #pragma unroll
        for (int mi = 0; mi < 4; mi++)
            a[mi] = *(const short8v*)&Al[(wm * 64 + mi * 16 + (lane & 15)) * 32 + (lane >> 4) * 8];
        #pragma unroll
        for (int ni = 0; ni < 4; ni++)
            b[ni] = *(const short8v*)&Bl[(wn * 64 + ni * 16 + (lane & 15)) * 32 + (lane >> 4) * 8];
        #pragma unroll
        for (int mi = 0; mi < 4; mi++)
            #pragma unroll
            for (int ni = 0; ni < 4; ni++)
                acc[mi][ni] = __builtin_amdgcn_mfma_f32_16x16x32_bf16(b[ni], a[mi], acc[mi][ni], 0, 0, 0);
        __syncthreads();
    }

    #pragma unroll
    for (int mi = 0; mi < 4; mi++) {
        const int i = i0 + wm * 64 + mi * 16 + (lane & 15);
        #pragma unroll
        for (int ni = 0; ni < 4; ni++) {
            const int sc0 = n0 + wn * 64 + ni * 16 + ((lane >> 4) << 2);
            const int s = sc0 >> 5, c0 = sc0 & 31;
            ushort4v o4;
            #pragma unroll
            for (int r = 0; r < 4; r++) o4[r] = f2bf(acc[mi][ni][r]);
            *(ushort4v*)&ob[((size_t)s * NN + i) * HC + (h << 5) + c0] = o4;
        }
    }
}

// ---------------- k5: out[98304,64] = (o .* g)[98304,256] @ w_out[256,64]  via MFMA ----------------
__global__ __launch_bounds__(256) void k5_mfma(
    const unsigned short* __restrict__ ob, const unsigned short* __restrict__ g,
    const float* __restrict__ w_out, float* __restrict__ out)
{
    __shared__ unsigned short WT[64 * 256];   // w_out^T bf16, swizzled: idx ^ ((c&7)<<3)
    const int tid = threadIdx.x, wid = tid >> 6, lane = tid & 63;
    #pragma unroll
    for (int e = 0; e < 16; e++) {
        int fidx = (tid + e * 256) * 4;
        float4 w4 = *(const float4*)&w_out[fidx];
        int k = fidx >> 6, c0 = fidx & 63;
        float wv[4] = {w4.x, w4.y, w4.z, w4.w};
        #pragma unroll
        for (int q = 0; q < 4; q++) {
            int c = c0 + q;
            WT[(((c << 8) + k)) ^ ((c & 7) << 3)] = f2bf(wv[q]);
        }
    }
    __syncthreads();

    const size_t rowbase = (size_t)blockIdx.x * 64 + wid * 16;
    const int arow = lane & 15, achunk = lane >> 4;
    const unsigned short* op = ob + (rowbase + arow) * HC + achunk * 8;
    const unsigned short* gp = g  + (rowbase + arow) * HC + achunk * 8;

    f32x4 acc[4] = {};
    #pragma unroll
    for (int ks = 0; ks < 8; ks++) {
        ushort8v o8 = *(const ushort8v*)(op + ks * 32);
        ushort8v g8 = *(const ushort8v*)(gp + ks * 32);
        short8v a;
        #pragma unroll
        for (int q = 0; q < 8; q++)
            a[q] = (short)f2bf(bf2f(o8[q]) * bf2f(g8[q]));
        #pragma unroll
        for (int nf = 0; nf < 4; nf++) {
            const int c = nf * 16 + arow;
            short8v b = *(const short8v*)&WT[(((c << 8) + ks * 32 + achunk * 8)) ^ ((c & 7) << 3)];
            acc[nf] = __builtin_amdgcn_mfma_f32_16x16x32_bf16(a, b, acc[nf], 0, 0, 0);
        }
    }
    #pragma unroll
    for (int nf = 0; nf < 4; nf++)
        #pragma unroll
        for (int r = 0; r < 4; r++)
            out[(rowbase + achunk * 4 + r) * CM + nf * 16 + arow] = acc[nf][r];
}

extern "C" void kernel_launch(void* const* d_in, const int* in_sizes, int n_in,
                              void* d_out, int out_size, void* d_ws, size_t ws_size,
                              hipStream_t stream)
{
    const float* m      = (const float*)d_in[0];
    const float* z      = (const float*)d_in[1];
    const unsigned int* mask_raw = (const unsigned int*)d_in[2];
    const float* ln_m_w = (const float*)d_in[3];
    const float* ln_m_b = (const float*)d_in[4];
    const float* ln_z_w = (const float*)d_in[5];
    const float* ln_z_b = (const float*)d_in[6];
    const float* w_v    = (const float*)d_in[7];
    const float* w_b    = (const float*)d_in[8];
    const float* w_g    = (const float*)d_in[9];
    const float* w_out  = (const float*)d_in[10];
    float* out = (float*)d_out;

    // ws layout
    float* mterm = (float*)d_ws;
    unsigned short* wbl = (unsigned short*)(mterm + 384);
    unsigned short* vT  = wbl + 1179648;
    unsigned short* g   = vT + NV;
    unsigned short* ob  = g + NV;
    unsigned short* BTg = ob + NV;             // [512][64]
    unsigned short* w2bf = BTg + 32768;        // [16][128]
    float* consts = (float*)(w2bf + 2048);     // [32]

    k_prep<<<130, 256, 0, stream>>>(mask_raw, ln_z_w, ln_z_b, w_b, w_v, w_g,
                                    mterm, w2bf, consts, BTg);
    k1b23<<<1920, 512, 0, stream>>>(BTg, m, ln_m_w, ln_m_b, vT, g,
                                    z, w2bf, consts, mterm, wbl);
    k4_mfma<<<dim3(64, 3, 8), 256, 0, stream>>>(wbl, vT, ob);
    k5_mfma<<<1536, 256, 0, stream>>>(ob, g, w_out, out);
}

// Round 25
// 123.262 us; speedup vs baseline: 1.0912x; 1.0049x over previous
//
#include <hip/hip_runtime.h>
#include <math.h>

// MSAPairWeightedAveraging — round 24: recombine best-measured pieces.
// dispatch1 = k_prep ∪ k1n (heterogeneous; mln materialized, aliased to ob);
// dispatch2 = k1b23 with r19's 45µs barrier-free mln-based k1b branch + k23 branch.
// S=256, N=384, C_M=64, C_Z=128, C=32, H=8, H*C=256.
// ws: mterm f32[384] | wbl bf16[8,384,384] | vT bf16[8,8192,384] | g bf16[98304,256]
//     | ob bf16[98304,256] (aliased as mln pre-k4) | BTg bf16[512,64] | w2bf bf16[16,128] | consts f32[32]

#define SS 256
#define NN 384
#define CM 64
#define CZ 128
#define HH 8
#define HC 256
#define NV 25165824   // S*N*HC

typedef __attribute__((ext_vector_type(8))) short short8v;
typedef __attribute__((ext_vector_type(8))) unsigned short ushort8v;
typedef __attribute__((ext_vector_type(4))) unsigned short ushort4v;
typedef __attribute__((ext_vector_type(4))) float f32x4;

static __device__ __forceinline__ float bf2f(unsigned short u) {
    union { unsigned int i; float f; } x; x.i = ((unsigned int)u) << 16; return x.f;
}
static __device__ __forceinline__ unsigned short f2bf(float f) {
    union { float f; unsigned int i; } x; x.f = f;
    unsigned int r = x.i + 0x7FFFu + ((x.i >> 16) & 1u);   // RNE
    return (unsigned short)(r >> 16);
}
static __device__ __forceinline__ void gload_lds16(const void* g, void* l) {
    __builtin_amdgcn_global_load_lds((const __attribute__((address_space(1))) void*)g,
                                     (__attribute__((address_space(3))) void*)l, 16, 0, 0);
}

// ---------------- dispatch1: {mask | w_b fold | w_v/w_g transpose | LN(m) -> mln} ----------------
// blocks 0..129 = k_prep bodies; blocks 130..1665 = k1n body (64 rows each).
__global__ __launch_bounds__(256) void k_prep1(
    const unsigned int* __restrict__ mu, const float* __restrict__ lnzw,
    const float* __restrict__ lnzb, const float* __restrict__ w_b,
    const float* __restrict__ w_v, const float* __restrict__ w_g,
    const float* __restrict__ m, const float* __restrict__ lnw, const float* __restrict__ lnb,
    float* __restrict__ mterm, unsigned short* __restrict__ w2bf,
    float* __restrict__ consts, unsigned short* __restrict__ BTg,
    unsigned short* __restrict__ mln)
{
    const int b = blockIdx.x, tid = threadIdx.x;
    if (b >= 130) {
        // ---- k1n: LN(m) -> mln bf16 [98304][64], pre-swizzled within rows ----
        const int wid = tid >> 6, lane = tid & 63;
        const int rowBase = (b - 130) * 64 + wid * 16;
        const float lw = lnw[lane], lb2 = lnb[lane];
        #pragma unroll 4
        for (int rr = 0; rr < 16; rr++) {
            int row = rowBase + rr;
            float x = m[(size_t)row * CM + lane];
            float s1 = x, s2 = x * x;
            #pragma unroll
            for (int off = 32; off; off >>= 1) {
                s1 += __shfl_xor(s1, off);
                s2 += __shfl_xor(s2, off);
            }
            float mu2  = s1 * (1.0f / CM);
            float var = s2 * (1.0f / CM) - mu2 * mu2;
            float y = (x - mu2) * rsqrtf(var + 1e-5f) * lw + lb2;
            mln[(size_t)row * CM + (lane ^ ((row & 7) << 3))] = f2bf(y);
        }
        return;
    }
    if (b == 0) {
        __shared__ int byteLayout;
        if (tid == 0) byteLayout = 0;
        __syncthreads();
        if (tid < 96) {
            unsigned int u = mu[tid];
            if (u != 0u && u != 1u && u != 0x3F800000u) atomicOr(&byteLayout, 1);
        }
        __syncthreads();
        for (int j = tid; j < 384; j += 256) {
            int val;
            if (byteLayout) val = ((const unsigned char*)mu)[j];
            else            val = (mu[j] != 0u);
            mterm[j] = val ? 0.0f : -1e9f;
        }
    } else if (b == 1) {
        __shared__ float pA[128][8], pB[128][8];
        const int c = tid & 127;
        if (tid < 128) {
            float lw = lnzw[c], lb2 = lnzb[c];
            float4 wb0 = *(const float4*)&w_b[c * 8];
            float4 wb1 = *(const float4*)&w_b[c * 8 + 4];
            float wv[8] = {wb0.x, wb0.y, wb0.z, wb0.w, wb1.x, wb1.y, wb1.z, wb1.w};
            #pragma unroll
            for (int h = 0; h < 8; h++) {
                w2bf[h * CZ + c]       = f2bf(lw * wv[h]);
                w2bf[(8 + h) * CZ + c] = 0;
                pA[c][h] = lw * wv[h];
                pB[c][h] = lb2 * wv[h];
            }
        }
        __syncthreads();
        if (tid < 8) {
            float A = 0.f, B = 0.f;
            for (int q = 0; q < 128; q++) { A += pA[q][tid]; B += pB[q][tid]; }
            consts[tid] = A; consts[16 + tid] = B;
            consts[8 + tid] = 0.f; consts[24 + tid] = 0.f;
        }
    } else {
        const int col = (b - 2) * 4 + (tid >> 6);
        const int k   = tid & 63;
        float w = (col < 256) ? w_v[k * 256 + col] : w_g[k * 256 + (col - 256)];
        BTg[col * 64 + (k ^ ((col & 7) << 3))] = f2bf(w);
    }
}

// ---------------- k1b23: heterogeneous {k23 | r19 barrier-free mln-based k1b} ----------------
// blocks 0..383:    k23 body (LN(z)@W2 + mask + softmax), i = blockIdx.x
// blocks 384..1919: k1b body (reads mln), rowBase = (blockIdx.x-384)*64, zero barriers
__global__ __launch_bounds__(512) void k1b23(
    const unsigned short* __restrict__ BTg, const unsigned short* __restrict__ mln,
    unsigned short* __restrict__ vT, unsigned short* __restrict__ gout,
    const float* __restrict__ z, const unsigned short* __restrict__ w2bf,
    const float* __restrict__ consts, const float* __restrict__ mterm,
    unsigned short* __restrict__ wbl)
{
    __shared__ unsigned short SMEM[36864];   // 72 KB union
    const int tid = threadIdx.x, wid = tid >> 6, lane = tid & 63;
    const int rl = lane & 15, kc = lane >> 4;

    if (blockIdx.x < 384) {
        // ================= k23 branch =================
        unsigned short* Llog = SMEM;          // [384][10] bf16, 7.5 KB
        const int i = blockIdx.x;

        short8v bf[4];
        #pragma unroll
        for (int ks = 0; ks < 4; ks++)
            bf[ks] = *(const short8v*)&w2bf[rl * CZ + ks * 32 + kc * 8];
        const float Ah = consts[rl], Bh = consts[16 + rl];

        #pragma unroll
        for (int ch = 0; ch < 3; ch++) {
            const int jb = wid * 48 + ch * 16;
            const float* zr = z + ((size_t)i * NN + jb + rl) * CZ + kc * 8;

            float s1 = 0.f, s2 = 0.f;
            short8v af[4];
            #pragma unroll
            for (int ks = 0; ks < 4; ks++) {
                float4 z0 = *(const float4*)(zr + ks * 32);
                float4 z1 = *(const float4*)(zr + ks * 32 + 4);
                float zz[8] = {z0.x, z0.y, z0.z, z0.w, z1.x, z1.y, z1.z, z1.w};
                short8v a;
                #pragma unroll
                for (int q = 0; q < 8; q++) {
                    s1 += zz[q];
                    s2 += zz[q] * zz[q];
                    a[q] = (short)f2bf(zz[q]);
                }
                af[ks] = a;
            }
            s1 += __shfl_xor(s1, 16); s2 += __shfl_xor(s2, 16);
            s1 += __shfl_xor(s1, 32); s2 += __shfl_xor(s2, 32);

            f32x4 acc = {};
            #pragma unroll
            for (int ks = 0; ks < 4; ks++)
                acc = __builtin_amdgcn_mfma_f32_16x16x32_bf16(af[ks], bf[ks], acc, 0, 0, 0);

            unsigned short pv[4];
            #pragma unroll
            for (int reg = 0; reg < 4; reg++) {
                int r = 4 * kc + reg;
                float S1 = __shfl(s1, r);
                float S2 = __shfl(s2, r);
                float mu   = S1 * (1.0f / CZ);
                float var  = S2 * (1.0f / CZ) - mu * mu;
                float rstd = rsqrtf(var + 1e-5f);
                float b = rstd * acc[reg] - rstd * mu * Ah + Bh + mterm[jb + r];
                pv[reg] = f2bf(b);
            }
            if (rl < 8) {
                #pragma unroll
                for (int reg = 0; reg < 4; reg++)
                    Llog[(jb + 4 * kc + reg) * 10 + rl] = pv[reg];
            }
        }
        __syncthreads();

        unsigned short* p = wbl + ((size_t)wid * NN + i) * NN;
        float x[6];
        float mx = -1e30f;
        #pragma unroll
        for (int e = 0; e < 6; e++) { x[e] = bf2f(Llog[(lane + e * 64) * 10 + wid]); mx = fmaxf(mx, x[e]); }
        #pragma unroll
        for (int off = 32; off; off >>= 1) mx = fmaxf(mx, __shfl_xor(mx, off));
        float sum = 0.f;
        #pragma unroll
        for (int e = 0; e < 6; e++) { x[e] = expf(x[e] - mx); sum += x[e]; }
        #pragma unroll
        for (int off = 32; off; off >>= 1) sum += __shfl_xor(sum, off);
        float inv = 1.0f / sum;
        #pragma unroll
        for (int e = 0; e < 6; e++) p[lane + e * 64] = f2bf(x[e] * inv);
        return;
    }

    // ================= k1b branch (r19-exact, reads mln, zero barriers) =================
    unsigned short* Wl = SMEM;            // [512 cols][64 k] swizzled; wave-partitioned (8KB/wave)
    unsigned short* Al = SMEM + 32768;    // [64 rows][64 k] swizzled; redundantly staged
    const int fam = wid >> 2, wq = wid & 3;
    const int rowBase = (blockIdx.x - 384) * 64;   // 64 | 384 -> never straddles s
    const int s = rowBase / NN, j0 = rowBase - s * NN;

    #pragma unroll
    for (int it = 0; it < 8; it++) {
        int eoff = wid * 4096 + it * 512;          // == (fam*16384 + wq*4096) + it*512
        gload_lds16(BTg + eoff + lane * 8, (void*)((char*)Wl + eoff * 2));
    }
    #pragma unroll
    for (int it = 0; it < 8; it++) {
        int eoff = it * 512;
        gload_lds16(mln + (size_t)rowBase * CM + eoff + lane * 8, (void*)((char*)Al + eoff * 2));
    }
    asm volatile("s_waitcnt vmcnt(0)" ::: "memory");
    __builtin_amdgcn_sched_barrier(0);

    short8v al[2][4];
    #pragma unroll
    for (int ks = 0; ks < 2; ks++)
        #pragma unroll
        for (int q = 0; q < 4; q++) {
            int row = q * 16 + rl;
            al[ks][q] = *(const short8v*)&Al[(row * 64 + ks * 32 + kc * 8) ^ ((row & 7) << 3)];
        }

    unsigned short* WP = Wl + wid * 4096;   // this wave's 8KB W region (cols local 0..63)
    unsigned short* VS = WP;                // reused as wave-private scratch after wf reads

    f32x4 acc[4][4] = {};
    if (fam == 0) {
        // v: A=al so j lands in reg dim
        #pragma unroll
        for (int ks = 0; ks < 2; ks++) {
            short8v wf[4];
            #pragma unroll
            for (int q = 0; q < 4; q++) {
                int cl = q * 16 + rl;   // local col; global col = wq*64+cl, (col&7)==(cl&7)
                wf[q] = *(const short8v*)&WP[(cl * 64 + ks * 32 + kc * 8) ^ ((cl & 7) << 3)];
            }
            #pragma unroll
            for (int mi = 0; mi < 4; mi++)
                #pragma unroll
                for (int nf = 0; nf < 4; nf++)
                    acc[mi][nf] = __builtin_amdgcn_mfma_f32_16x16x32_bf16(al[ks][mi], wf[nf], acc[mi][nf], 0, 0, 0);
        }
        #pragma unroll
        for (int mi = 0; mi < 4; mi++) {
            const int jb = mi * 16 + kc * 4;
            #pragma unroll
            for (int nf = 0; nf < 4; nf++) {
                int hcl = nf * 16 + rl;
                ushort4v o4;
                #pragma unroll
                for (int r = 0; r < 4; r++) o4[r] = f2bf(acc[mi][nf][r]);
                *(ushort4v*)&VS[(hcl * 64 + jb) ^ ((hcl & 7) << 3)] = o4;
            }
        }
        #pragma unroll
        for (int p = 0; p < 8; p++) {
            int hcl = p * 8 + (lane >> 3);
            int j8  = (lane & 7) * 8;
            ushort8v val = *(const ushort8v*)&VS[(hcl * 64 + j8) ^ ((hcl & 7) << 3)];
            int hc = wq * 64 + hcl;
            size_t vrow = (size_t)((hc >> 5) * 8192 + s * 32 + (hc & 31));
            *(ushort8v*)&vT[vrow * NN + j0 + j8] = val;
        }
    } else {
        // g: A=wf so hc lands in reg dim
        #pragma unroll
        for (int ks = 0; ks < 2; ks++) {
            short8v wf[4];
            #pragma unroll
            for (int q = 0; q < 4; q++) {
                int cl = q * 16 + rl;
                wf[q] = *(const short8v*)&WP[(cl * 64 + ks * 32 + kc * 8) ^ ((cl & 7) << 3)];
            }
            #pragma unroll
            for (int mi = 0; mi < 4; mi++)
                #pragma unroll
                for (int nf = 0; nf < 4; nf++)
                    acc[mi][nf] = __builtin_amdgcn_mfma_f32_16x16x32_bf16(wf[mi], al[ks][nf], acc[mi][nf], 0, 0, 0);
        }
        #pragma unroll
        for (int mi = 0; mi < 4; mi++) {
            const int hcb = mi * 16 + kc * 4;   // local hc 0..63
            #pragma unroll
            for (int nf = 0; nf < 4; nf++) {
                int rowl = nf * 16 + rl;
                ushort4v o4;
                #pragma unroll
                for (int r = 0; r < 4; r++)
                    o4[r] = f2bf(1.0f / (1.0f + __expf(-acc[mi][nf][r])));
                *(ushort4v*)&VS[(rowl * 64 + hcb) ^ ((rowl & 7) << 3)] = o4;
            }
        }
        #pragma unroll
        for (int p = 0; p < 8; p++) {
            int rowl = p * 8 + (lane >> 3);
            int hc8  = (lane & 7) * 8;
            ushort8v val = *(const ushort8v*)&VS[(rowl * 64 + hc8) ^ ((rowl & 7) << 3)];
            *(ushort8v*)&gout[(size_t)(rowBase + rowl) * HC + wq * 64 + hc8] = val;
        }
    }
}

// ---------------- k4: per-h MFMA GEMM; operand-swapped -> packed 8B ob stores ----------------
__global__ __launch_bounds__(256) void k4_mfma(
    const unsigned short* __restrict__ wbf, const unsigned short* __restrict__ vT,
    unsigned short* __restrict__ ob)
{
    __shared__ unsigned short Al[128 * 32];
    __shared__ unsigned short Bl[128 * 32];
    const int tid  = threadIdx.x;
    const int wid  = tid >> 6, lane = tid & 63;
    const int wm   = wid >> 1, wn = wid & 1;
    const int h    = blockIdx.z;
    const int i0   = blockIdx.y * 128;
    const int n0   = blockIdx.x * 128;
    const unsigned short* Ag = wbf + (size_t)h * NN * NN;
    const unsigned short* Bg = vT  + (size_t)h * 8192 * NN;

    f32x4 acc[4][4] = {};

    const int lrow = lane >> 2, lchunk = lane & 3;
    for (int k0 = 0; k0 < NN; k0 += 32) {
        #pragma unroll
        for (int q = 0; q < 2; q++) {
            int issue = wid * 2 + q;
            int r = issue * 16 + lrow;
            gload_lds16(Ag + (size_t)(i0 + r) * NN + k0 + lchunk * 8,
                        (void*)((char*)Al + issue * 1024));
            gload_lds16(Bg + (size_t)(n0 + r) * NN + k0 + lchunk * 8,
                        (void*)((char*)Bl + issue * 1024));
        }
        __syncthreads();

        short8v a[4], b[4];
        #pragma unroll
        for (int mi = 0; mi < 4; mi++)
            a[mi] = *(const short8v*)&Al[(wm * 64 + mi * 16 + (lane & 15)) * 32 + (lane >> 4) * 8];
        #pragma unroll
        for (int ni = 0; ni < 4; ni++)
            b[ni] = *(const short8v*)&Bl[(wn * 64 + ni * 16 + (lane & 15)) * 32 + (lane >> 4) * 8];
        #pragma unroll
        for (int mi = 0; mi < 4; mi++)
            #pragma unroll
            for (int ni = 0; ni < 4; ni++)
                acc[mi][ni] = __builtin_amdgcn_mfma_f32_16x16x32_bf16(b[ni], a[mi], acc[mi][ni], 0, 0, 0);
        __syncthreads();
    }

    #pragma unroll
    for (int mi = 0; mi < 4; mi++) {
        const int i = i0 + wm * 64 + mi * 16 + (lane & 15);
        #pragma unroll
        for (int ni = 0; ni < 4; ni++) {
            const int sc0 = n0 + wn * 64 + ni * 16 + ((lane >> 4) << 2);
            const int s = sc0 >> 5, c0 = sc0 & 31;
            ushort4v o4;
            #pragma unroll
            for (int r = 0; r < 4; r++) o4[r] = f2bf(acc[mi][ni][r]);
            *(ushort4v*)&ob[((size_t)s * NN + i) * HC + (h << 5) + c0] = o4;
        }
    }
}

// ---------------- k5: out[98304,64] = (o .* g)[98304,256] @ w_out[256,64]  via MFMA ----------------
__global__ __launch_bounds__(256) void k5_mfma(
    const unsigned short* __restrict__ ob, const unsigned short* __restrict__ g,
    const float* __restrict__ w_out, float* __restrict__ out)
{
    __shared__ unsigned short WT[64 * 256];   // w_out^T bf16, swizzled: idx ^ ((c&7)<<3)
    const int tid = threadIdx.x, wid = tid >> 6, lane = tid & 63;
    #pragma unroll
    for (int e = 0; e < 16; e++) {
        int fidx = (tid + e * 256) * 4;
        float4 w4 = *(const float4*)&w_out[fidx];
        int k = fidx >> 6, c0 = fidx & 63;
        float wv[4] = {w4.x, w4.y, w4.z, w4.w};
        #pragma unroll
        for (int q = 0; q < 4; q++) {
            int c = c0 + q;
            WT[(((c << 8) + k)) ^ ((c & 7) << 3)] = f2bf(wv[q]);
        }
    }
    __syncthreads();

    const size_t rowbase = (size_t)blockIdx.x * 64 + wid * 16;
    const int arow = lane & 15, achunk = lane >> 4;
    const unsigned short* op = ob + (rowbase + arow) * HC + achunk * 8;
    const unsigned short* gp = g  + (rowbase + arow) * HC + achunk * 8;

    f32x4 acc[4] = {};
    #pragma unroll
    for (int ks = 0; ks < 8; ks++) {
        ushort8v o8 = *(const ushort8v*)(op + ks * 32);
        ushort8v g8 = *(const ushort8v*)(gp + ks * 32);
        short8v a;
        #pragma unroll
        for (int q = 0; q < 8; q++)
            a[q] = (short)f2bf(bf2f(o8[q]) * bf2f(g8[q]));
        #pragma unroll
        for (int nf = 0; nf < 4; nf++) {
            const int c = nf * 16 + arow;
            short8v b = *(const short8v*)&WT[(((c << 8) + ks * 32 + achunk * 8)) ^ ((c & 7) << 3)];
            acc[nf] = __builtin_amdgcn_mfma_f32_16x16x32_bf16(a, b, acc[nf], 0, 0, 0);
        }
    }
    #pragma unroll
    for (int nf = 0; nf < 4; nf++)
        #pragma unroll
        for (int r = 0; r < 4; r++)
            out[(rowbase + achunk * 4 + r) * CM + nf * 16 + arow] = acc[nf][r];
}

extern "C" void kernel_launch(void* const* d_in, const int* in_sizes, int n_in,
                              void* d_out, int out_size, void* d_ws, size_t ws_size,
                              hipStream_t stream)
{
    const float* m      = (const float*)d_in[0];
    const float* z      = (const float*)d_in[1];
    const unsigned int* mask_raw = (const unsigned int*)d_in[2];
    const float* ln_m_w = (const float*)d_in[3];
    const float* ln_m_b = (const float*)d_in[4];
    const float* ln_z_w = (const float*)d_in[5];
    const float* ln_z_b = (const float*)d_in[6];
    const float* w_v    = (const float*)d_in[7];
    const float* w_b    = (const float*)d_in[8];
    const float* w_g    = (const float*)d_in[9];
    const float* w_out  = (const float*)d_in[10];
    float* out = (float*)d_out;

    // ws layout
    float* mterm = (float*)d_ws;
    unsigned short* wbl = (unsigned short*)(mterm + 384);
    unsigned short* vT  = wbl + 1179648;
    unsigned short* g   = vT + NV;
    unsigned short* ob  = g + NV;
    unsigned short* BTg = ob + NV;             // [512][64]
    unsigned short* w2bf = BTg + 32768;        // [16][128]
    float* consts = (float*)(w2bf + 2048);     // [32]
    unsigned short* mln = ob;                  // alias: dead before k4 writes ob

    k_prep1<<<1666, 256, 0, stream>>>(mask_raw, ln_z_w, ln_z_b, w_b, w_v, w_g,
                                      m, ln_m_w, ln_m_b,
                                      mterm, w2bf, consts, BTg, mln);
    k1b23<<<1920, 512, 0, stream>>>(BTg, mln, vT, g, z, w2bf, consts, mterm, wbl);
    k4_mfma<<<dim3(64, 3, 8), 256, 0, stream>>>(wbl, vT, ob);
    k5_mfma<<<1536, 256, 0, stream>>>(ob, g, w_out, out);
}